// Round 5
// baseline (22950.514 us; speedup 1.0000x reference)
//
#include <hip/hip_runtime.h>

#define DEVI __device__ __forceinline__

DEVI float sigm(float x){ return 1.0f / (1.0f + __expf(-x)); }
DEVI float tanh_f(float x){ return 1.0f - 2.0f / (1.0f + __expf(2.0f * x)); }

// One block = 32 samples. Pure f32 scalar implementation (correctness baseline).
// Output is FLOAT32 (the reference's output dtype).
// Thread roles:
//   gate phases:  u_ = tid & 255 (unit), sh = tid >> 8 (sample half, 16 samples each)
//   row phases:   sA = tid >> 4 (sample), cb = tid & 15 (column block)
__global__ __launch_bounds__(512, 1) void vae_scalar(
    const float* __restrict__ x, const float* __restrict__ eps,
    const float* __restrict__ Wee, const float* __restrict__ bee,
    const float* __restrict__ Wihf, const float* __restrict__ Whhf,
    const float* __restrict__ bihf, const float* __restrict__ bhhf,
    const float* __restrict__ Wihb,
    const float* __restrict__ bihb, const float* __restrict__ bhhb,
    const float* __restrict__ Wenc, const float* __restrict__ benc,
    const float* __restrict__ Wz2h, const float* __restrict__ bz2h,
    const float* __restrict__ Wh2i, const float* __restrict__ bh2i,
    const float* __restrict__ Wihd, const float* __restrict__ Whhd,
    const float* __restrict__ bihd, const float* __restrict__ bhhd,
    const float* __restrict__ Wed, const float* __restrict__ bed,
    const float* __restrict__ Wdec, const float* __restrict__ bdec,
    float* __restrict__ out)
{
  __shared__ float XEI[32 * 132];   // xe_t (enc) / z (cols 0..63) / inp (dec, 128 cols)
  __shared__ float HH [32 * 264];   // recurrent h (256 cols)
  __shared__ float HB [32 * 264];   // h_bwd
  __shared__ float ST [32 * 132];   // stats (128 cols)
  __shared__ float XC [32 * 36];    // x_cur (32 cols)

  const int tid = threadIdx.x;
  const int s0 = blockIdx.x * 32;
  const int u_ = tid & 255, sh = tid >> 8;
  const int sA = tid >> 4, cb = tid & 15;

  const float brf = bihf[u_] + bhhf[u_], bzf = bihf[256+u_] + bhhf[256+u_];
  const float binf = bihf[512+u_], bhnf = bhhf[512+u_];
  const float brb = bihb[u_] + bhhb[u_], bzb = bihb[256+u_] + bhhb[256+u_];
  const float binb = bihb[512+u_], bhnb = bhhb[512+u_];
  const float brd = bihd[u_] + bhhd[u_], bzd = bihd[256+u_] + bhhd[256+u_];
  const float bind = bihd[512+u_], bhnd = bhhd[512+u_];

  float hreg[16];
  #pragma unroll
  for (int i = 0; i < 16; ++i) hreg[i] = 0.f;

  for (int i = tid; i < 32 * 264; i += 512) HH[i] = 0.f;
  __syncthreads();

  float accr[16], accz[16], accni[16], accnh[16];

  // ======================= encoder: 100 steps =======================
  for (int t = 0; t < 100; ++t){
    // ---- P_XE: xe_t = relu(x_t @ W_ee + b_ee) -> XEI ----
    {
      float xr[32];
      const float* xp = x + (size_t)(s0 + sA) * 3200 + t * 32;
      #pragma unroll
      for (int k = 0; k < 32; k += 4) *(float4*)&xr[k] = *(const float4*)(xp + k);
      float acc[8];
      #pragma unroll
      for (int j = 0; j < 8; ++j) acc[j] = bee[cb*8 + j];
      for (int k = 0; k < 32; ++k){
        const float xv = xr[k];
        const float4 w0 = *(const float4*)&Wee[k*128 + cb*8];
        const float4 w1 = *(const float4*)&Wee[k*128 + cb*8 + 4];
        acc[0]+=xv*w0.x; acc[1]+=xv*w0.y; acc[2]+=xv*w0.z; acc[3]+=xv*w0.w;
        acc[4]+=xv*w1.x; acc[5]+=xv*w1.y; acc[6]+=xv*w1.z; acc[7]+=xv*w1.w;
      }
      #pragma unroll
      for (int j = 0; j < 8; ++j) XEI[sA*132 + cb*8 + j] = fmaxf(acc[j], 0.f);
    }
    __syncthreads();

    // ---- P_ACC: gate dot products ----
    {
      #pragma unroll
      for (int i = 0; i < 16; ++i){ accr[i]=0.f; accz[i]=0.f; accni[i]=0.f; accnh[i]=0.f; }
      for (int k4 = 0; k4 < 128; k4 += 4){
        float wr[4], wz[4], wn[4];
        #pragma unroll
        for (int j = 0; j < 4; ++j){
          wr[j] = Wihf[(k4+j)*768 + u_];
          wz[j] = Wihf[(k4+j)*768 + 256 + u_];
          wn[j] = Wihf[(k4+j)*768 + 512 + u_];
        }
        #pragma unroll
        for (int i = 0; i < 16; ++i){
          const float4 xq = *(const float4*)&XEI[(sh*16+i)*132 + k4];
          accr[i]  += xq.x*wr[0] + xq.y*wr[1] + xq.z*wr[2] + xq.w*wr[3];
          accz[i]  += xq.x*wz[0] + xq.y*wz[1] + xq.z*wz[2] + xq.w*wz[3];
          accni[i] += xq.x*wn[0] + xq.y*wn[1] + xq.z*wn[2] + xq.w*wn[3];
        }
      }
      for (int k4 = 0; k4 < 256; k4 += 4){
        float wr[4], wz[4], wn[4];
        #pragma unroll
        for (int j = 0; j < 4; ++j){
          wr[j] = Whhf[(k4+j)*768 + u_];
          wz[j] = Whhf[(k4+j)*768 + 256 + u_];
          wn[j] = Whhf[(k4+j)*768 + 512 + u_];
        }
        #pragma unroll
        for (int i = 0; i < 16; ++i){
          const float4 hq = *(const float4*)&HH[(sh*16+i)*264 + k4];
          accr[i]  += hq.x*wr[0] + hq.y*wr[1] + hq.z*wr[2] + hq.w*wr[3];
          accz[i]  += hq.x*wz[0] + hq.y*wz[1] + hq.z*wz[2] + hq.w*wz[3];
          accnh[i] += hq.x*wn[0] + hq.y*wn[1] + hq.z*wn[2] + hq.w*wn[3];
        }
      }
    }
    __syncthreads();

    // ---- P_COMB ----
    #pragma unroll
    for (int i = 0; i < 16; ++i){
      const float r  = sigm(accr[i] + brf);
      const float zz = sigm(accz[i] + bzf);
      const float n  = tanh_f(accni[i] + binf + r * (accnh[i] + bhnf));
      const float h  = (1.f - zz) * n + zz * hreg[i];
      hreg[i] = h;
      HH[(sh*16+i)*264 + u_] = h;
    }
    __syncthreads();
  }

  // ======================= backward cell (xe_99 in XEI, h0=0) =======================
  {
    #pragma unroll
    for (int i = 0; i < 16; ++i){ accr[i]=0.f; accz[i]=0.f; accni[i]=0.f; }
    for (int k4 = 0; k4 < 128; k4 += 4){
      float wr[4], wz[4], wn[4];
      #pragma unroll
      for (int j = 0; j < 4; ++j){
        wr[j] = Wihb[(k4+j)*768 + u_];
        wz[j] = Wihb[(k4+j)*768 + 256 + u_];
        wn[j] = Wihb[(k4+j)*768 + 512 + u_];
      }
      #pragma unroll
      for (int i = 0; i < 16; ++i){
        const float4 xq = *(const float4*)&XEI[(sh*16+i)*132 + k4];
        accr[i]  += xq.x*wr[0] + xq.y*wr[1] + xq.z*wr[2] + xq.w*wr[3];
        accz[i]  += xq.x*wz[0] + xq.y*wz[1] + xq.z*wz[2] + xq.w*wz[3];
        accni[i] += xq.x*wn[0] + xq.y*wn[1] + xq.z*wn[2] + xq.w*wn[3];
      }
    }
    #pragma unroll
    for (int i = 0; i < 16; ++i){
      const float r  = sigm(accr[i] + brb);
      const float zz = sigm(accz[i] + bzb);
      const float n  = tanh_f(accni[i] + binb + r * bhnb);   // h0=0 => hn = bhh_b
      HB[(sh*16+i)*264 + u_] = (1.f - zz) * n;
    }
  }
  __syncthreads();

  // ======================= stats = [h_fwd | h_bwd] @ W_enc + b_enc =======================
  {
    float acc[8];
    #pragma unroll
    for (int j = 0; j < 8; ++j) acc[j] = benc[cb*8 + j];
    for (int k = 0; k < 256; ++k){
      const float hv = HH[sA*264 + k];
      const float4 w0 = *(const float4*)&Wenc[k*128 + cb*8];
      const float4 w1 = *(const float4*)&Wenc[k*128 + cb*8 + 4];
      acc[0]+=hv*w0.x; acc[1]+=hv*w0.y; acc[2]+=hv*w0.z; acc[3]+=hv*w0.w;
      acc[4]+=hv*w1.x; acc[5]+=hv*w1.y; acc[6]+=hv*w1.z; acc[7]+=hv*w1.w;
    }
    for (int k = 0; k < 256; ++k){
      const float hv = HB[sA*264 + k];
      const float4 w0 = *(const float4*)&Wenc[(256+k)*128 + cb*8];
      const float4 w1 = *(const float4*)&Wenc[(256+k)*128 + cb*8 + 4];
      acc[0]+=hv*w0.x; acc[1]+=hv*w0.y; acc[2]+=hv*w0.z; acc[3]+=hv*w0.w;
      acc[4]+=hv*w1.x; acc[5]+=hv*w1.y; acc[6]+=hv*w1.z; acc[7]+=hv*w1.w;
    }
    #pragma unroll
    for (int j = 0; j < 8; ++j) ST[sA*132 + cb*8 + j] = acc[j];
  }
  __syncthreads();

  // ======================= z; write mu/logvar (f32) =======================
  {
    const int j0 = cb * 4;
    #pragma unroll
    for (int i = 0; i < 4; ++i){
      const int j = j0 + i;
      const float mu = ST[sA*132 + j], lv = ST[sA*132 + 64 + j];
      out[6553600u + (size_t)(s0 + sA)*64 + j] = mu;
      out[6684672u + (size_t)(s0 + sA)*64 + j] = lv;
      const float zv = mu + __expf(0.5f * lv) * eps[(size_t)(s0 + sA)*64 + j];
      XEI[sA*132 + j] = zv;
    }
  }
  __syncthreads();

  // ======================= h_dec0 = relu(z @ W_z2h + b_z2h) =======================
  {
    float acc[16];
    #pragma unroll
    for (int i = 0; i < 16; ++i) acc[i] = bz2h[u_];
    for (int k4 = 0; k4 < 64; k4 += 4){
      float wv[4];
      #pragma unroll
      for (int j = 0; j < 4; ++j) wv[j] = Wz2h[(k4+j)*256 + u_];
      #pragma unroll
      for (int i = 0; i < 16; ++i){
        const float4 zq = *(const float4*)&XEI[(sh*16+i)*132 + k4];
        acc[i] += zq.x*wv[0] + zq.y*wv[1] + zq.z*wv[2] + zq.w*wv[3];
      }
    }
    #pragma unroll
    for (int i = 0; i < 16; ++i){
      const float v = fmaxf(acc[i], 0.f);
      hreg[i] = v;                       // decoder carry (f32)
      HH[(sh*16+i)*264 + u_] = v;
    }
  }
  __syncthreads();

  // ======================= inp0 = [relu(b_ed) | relu(h_dec0 @ W_h2i + b_h2i)] =======================
  {
    float ah[4];
    #pragma unroll
    for (int i = 0; i < 4; ++i) ah[i] = bh2i[cb*4 + i];
    for (int k = 0; k < 256; ++k){
      const float hv = HH[sA*264 + k];
      const float4 wq = *(const float4*)&Wh2i[k*64 + cb*4];
      ah[0]+=hv*wq.x; ah[1]+=hv*wq.y; ah[2]+=hv*wq.z; ah[3]+=hv*wq.w;
    }
    #pragma unroll
    for (int i = 0; i < 4; ++i){
      XEI[sA*132 + 64 + cb*4 + i] = fmaxf(ah[i], 0.f);
      XEI[sA*132 + cb*4 + i]      = fmaxf(bed[cb*4 + i], 0.f);
    }
  }
  __syncthreads();

  // ======================= decoder: 100 steps =======================
  for (int t = 0; t < 100; ++t){
    // ---- P_ACC ----
    {
      #pragma unroll
      for (int i = 0; i < 16; ++i){ accr[i]=0.f; accz[i]=0.f; accni[i]=0.f; accnh[i]=0.f; }
      for (int k4 = 0; k4 < 128; k4 += 4){
        float wr[4], wz[4], wn[4];
        #pragma unroll
        for (int j = 0; j < 4; ++j){
          wr[j] = Wihd[(k4+j)*768 + u_];
          wz[j] = Wihd[(k4+j)*768 + 256 + u_];
          wn[j] = Wihd[(k4+j)*768 + 512 + u_];
        }
        #pragma unroll
        for (int i = 0; i < 16; ++i){
          const float4 xq = *(const float4*)&XEI[(sh*16+i)*132 + k4];
          accr[i]  += xq.x*wr[0] + xq.y*wr[1] + xq.z*wr[2] + xq.w*wr[3];
          accz[i]  += xq.x*wz[0] + xq.y*wz[1] + xq.z*wz[2] + xq.w*wz[3];
          accni[i] += xq.x*wn[0] + xq.y*wn[1] + xq.z*wn[2] + xq.w*wn[3];
        }
      }
      for (int k4 = 0; k4 < 256; k4 += 4){
        float wr[4], wz[4], wn[4];
        #pragma unroll
        for (int j = 0; j < 4; ++j){
          wr[j] = Whhd[(k4+j)*768 + u_];
          wz[j] = Whhd[(k4+j)*768 + 256 + u_];
          wn[j] = Whhd[(k4+j)*768 + 512 + u_];
        }
        #pragma unroll
        for (int i = 0; i < 16; ++i){
          const float4 hq = *(const float4*)&HH[(sh*16+i)*264 + k4];
          accr[i]  += hq.x*wr[0] + hq.y*wr[1] + hq.z*wr[2] + hq.w*wr[3];
          accz[i]  += hq.x*wz[0] + hq.y*wz[1] + hq.z*wz[2] + hq.w*wz[3];
          accnh[i] += hq.x*wn[0] + hq.y*wn[1] + hq.z*wn[2] + hq.w*wn[3];
        }
      }
    }
    __syncthreads();

    // ---- P_COMB ----
    #pragma unroll
    for (int i = 0; i < 16; ++i){
      const float r  = sigm(accr[i] + brd);
      const float zz = sigm(accz[i] + bzd);
      const float n  = tanh_f(accni[i] + bind + r * (accnh[i] + bhnd));
      const float h  = (1.f - zz) * n + zz * hreg[i];
      hreg[i] = h;
      HH[(sh*16+i)*264 + u_] = h;
    }
    __syncthreads();

    // ---- P_XCUR: x_cur = h2 @ W_dec + b_dec -> out (f32), XC ----
    {
      const int c0 = cb * 2;
      float a0 = bdec[c0], a1 = bdec[c0 + 1];
      for (int k = 0; k < 256; ++k){
        const float hv = HH[sA*264 + k];
        a0 += hv * Wdec[k*32 + c0];
        a1 += hv * Wdec[k*32 + c0 + 1];
      }
      const size_t o = (size_t)(s0 + sA)*3200 + t*32 + c0;
      out[o]     = a0;
      out[o + 1] = a1;
      XC[sA*36 + c0]     = a0;
      XC[sA*36 + c0 + 1] = a1;
    }
    __syncthreads();

    // ---- P_NEXTINP ----
    if (t < 99){
      float ah[4];
      #pragma unroll
      for (int i = 0; i < 4; ++i) ah[i] = bh2i[cb*4 + i];
      for (int k = 0; k < 256; ++k){
        const float hv = HH[sA*264 + k];
        const float4 wq = *(const float4*)&Wh2i[k*64 + cb*4];
        ah[0]+=hv*wq.x; ah[1]+=hv*wq.y; ah[2]+=hv*wq.z; ah[3]+=hv*wq.w;
      }
      float ac[4];
      #pragma unroll
      for (int i = 0; i < 4; ++i) ac[i] = bed[cb*4 + i];
      for (int k = 0; k < 32; ++k){
        const float xv = XC[sA*36 + k];
        const float4 wq = *(const float4*)&Wed[k*64 + cb*4];
        ac[0]+=xv*wq.x; ac[1]+=xv*wq.y; ac[2]+=xv*wq.z; ac[3]+=xv*wq.w;
      }
      #pragma unroll
      for (int i = 0; i < 4; ++i){
        XEI[sA*132 + 64 + cb*4 + i] = fmaxf(ah[i], 0.f);
        XEI[sA*132 + cb*4 + i]      = fmaxf(ac[i], 0.f);
      }
    }
    __syncthreads();
  }
}

extern "C" void kernel_launch(void* const* d_in, const int* in_sizes, int n_in,
                              void* d_out, int out_size, void* d_ws, size_t ws_size,
                              hipStream_t stream)
{
  (void)in_sizes; (void)n_in; (void)out_size; (void)d_ws; (void)ws_size;

  const float* x    = (const float*)d_in[0];
  const float* eps  = (const float*)d_in[1];
  const float* Wee  = (const float*)d_in[2];
  const float* bee  = (const float*)d_in[3];
  const float* Wihf = (const float*)d_in[4];
  const float* Whhf = (const float*)d_in[5];
  const float* bihf = (const float*)d_in[6];
  const float* bhhf = (const float*)d_in[7];
  const float* Wihb = (const float*)d_in[8];
  const float* bihb = (const float*)d_in[10];
  const float* bhhb = (const float*)d_in[11];
  const float* Wenc = (const float*)d_in[12];
  const float* benc = (const float*)d_in[13];
  const float* Wz2h = (const float*)d_in[14];
  const float* bz2h = (const float*)d_in[15];
  const float* Wh2i = (const float*)d_in[16];
  const float* bh2i = (const float*)d_in[17];
  const float* Wihd = (const float*)d_in[18];
  const float* Whhd = (const float*)d_in[19];
  const float* bihd = (const float*)d_in[20];
  const float* bhhd = (const float*)d_in[21];
  const float* Wed  = (const float*)d_in[22];
  const float* bed  = (const float*)d_in[23];
  const float* Wdec = (const float*)d_in[24];
  const float* bdec = (const float*)d_in[25];

  vae_scalar<<<64, 512, 0, stream>>>(x, eps, Wee, bee, Wihf, Whhf, bihf, bhhf,
                                     Wihb, bihb, bhhb, Wenc, benc, Wz2h, bz2h,
                                     Wh2i, bh2i, Wihd, Whhd, bihd, bhhd,
                                     Wed, bed, Wdec, bdec, (float*)d_out);
}

// Round 6
// 5828.369 us; speedup vs baseline: 3.9377x; 3.9377x over previous
//
#include <hip/hip_runtime.h>
#include <hip/hip_bf16.h>

typedef __bf16 bf16x8 __attribute__((ext_vector_type(8)));
typedef float  f32x4  __attribute__((ext_vector_type(4)));
typedef unsigned short u16;

#define DEVI __device__ __forceinline__

DEVI u16 f2bf(float f){
  unsigned u = __builtin_bit_cast(unsigned, f);
  u += 0x7fffu + ((u >> 16) & 1u);
  return (u16)(u >> 16);
}
DEVI float bf2f(u16 h){
  unsigned u = ((unsigned)h) << 16;
  return __builtin_bit_cast(float, u);
}

// ---- ws layout (bytes); all segments bf16, plain (identity) column order ----
enum : int {
  OFF_IHF = 0,                       // Wih_f: (128,768)  KT=4
  OFF_HHF = 196608,                  // Whh_f: (256,768)  KT=8
  OFF_IHB = 589824,                  // Wih_b: (128,768)  KT=4
  OFF_IHD = 786432,                  // Wih_d: (128,768)  KT=4
  OFF_HHD = 983040,                  // Whh_d: (256,768)  KT=8
  OFF_ENC = 1376256,                 // W_enc: (512,128)  KT=16
  OFF_Z2H = 1507328,                 // W_z2h: (64,256)   KT=2
  OFF_H2I = 1540096,                 // W_h2i: (256,64)   KT=8
  OFF_DEC = 1572864,                 // W_dec: (256,32)   KT=8
  OFF_EE  = 1589248,                 // W_ee : (32,128)   KT=1
  OFF_ED  = 1597440,                 // W_ed : (32,64)    KT=1
  WS_TOTAL = 1601536
};

// Pack W (K x N, row-major f32) into MFMA B-fragments:
// fragment f = ntg*KT + kt covers output cols [16*ntg,16*ntg+16), k in [kt*32,kt*32+32).
// lane l, elem j holds W[kt*32 + (l>>4)*8 + j][16*ntg + (l&15)].
DEVI void packseg(const float* __restrict__ W, u16* __restrict__ dst, int li, int N, int KT){
  int j = li & 7, l = (li >> 3) & 63, f = li >> 9;
  int kt = f % KT, ntg = f / KT;
  int k = kt * 32 + ((l >> 4) << 3) + j;
  int col = (ntg << 4) + (l & 15);
  dst[li] = f2bf(W[k * N + col]);
}

__global__ void pack_all(const float* Wihf, const float* Whhf, const float* Wihb,
                         const float* Wihd, const float* Whhd, const float* Wenc,
                         const float* Wz2h, const float* Wh2i, const float* Wdec,
                         const float* Wee,  const float* Wed, char* ws)
{
  int idx = blockIdx.x * 256 + threadIdx.x;
  if (idx < 98304) { packseg(Wihf, (u16*)(ws+OFF_IHF), idx, 768, 4); return; } idx -= 98304;
  if (idx < 196608){ packseg(Whhf, (u16*)(ws+OFF_HHF), idx, 768, 8); return; } idx -= 196608;
  if (idx < 98304) { packseg(Wihb, (u16*)(ws+OFF_IHB), idx, 768, 4); return; } idx -= 98304;
  if (idx < 98304) { packseg(Wihd, (u16*)(ws+OFF_IHD), idx, 768, 4); return; } idx -= 98304;
  if (idx < 196608){ packseg(Whhd, (u16*)(ws+OFF_HHD), idx, 768, 8); return; } idx -= 196608;
  if (idx < 65536) { packseg(Wenc, (u16*)(ws+OFF_ENC), idx, 128, 16); return; } idx -= 65536;
  if (idx < 16384) { packseg(Wz2h, (u16*)(ws+OFF_Z2H), idx, 256, 2); return; } idx -= 16384;
  if (idx < 16384) { packseg(Wh2i, (u16*)(ws+OFF_H2I), idx, 64, 8); return; } idx -= 16384;
  if (idx < 8192)  { packseg(Wdec, (u16*)(ws+OFF_DEC), idx, 32, 8); return; } idx -= 8192;
  if (idx < 4096)  { packseg(Wee,  (u16*)(ws+OFF_EE),  idx, 128, 1); return; } idx -= 4096;
  if (idx < 2048)  { packseg(Wed,  (u16*)(ws+OFF_ED),  idx, 64, 1); }
}

// ---- padded-row LDS helpers (rows padded +16B => 2-way bank alias, free) ----
enum : int { RB_G = 2064, RB_A1 = 272, RB_A2 = 528, RB_X = 80, ST_W = 132 };

DEVI bf16x8 ldF(const char* buf, int row, int kElem, int rowB){
  return *(const bf16x8*)(buf + row * rowB + kElem * 2);
}
DEVI void stBf(char* buf, int row, int col, int rowB, float v){
  *(u16*)(buf + row * rowB + col * 2) = f2bf(v);
}
DEVI float ldBf1(const char* buf, int row, int col, int rowB){
  return bf2f(*(const u16*)(buf + row * rowB + col * 2));
}

DEVI float sigm(float x){ return 1.0f / (1.0f + __expf(-x)); }
DEVI float tanh_f(float x){ return 1.0f - 2.0f / (1.0f + __expf(2.0f * x)); }

// stage x[:, t, :] (32 samples x 32 dims) into Xb
DEVI void stage_x(const float* __restrict__ xg, int s0, int t, char* Xb, int tid){
  int s = tid >> 4, d0 = (tid & 15) * 2;
  float2 v = *(const float2*)(xg + (size_t)(s0 + s) * 3200 + t * 32 + d0);
  unsigned pk = (unsigned)f2bf(v.x) | ((unsigned)f2bf(v.y) << 16);
  *(unsigned*)(Xb + s * RB_X + d0 * 2) = pk;
}

__global__ __launch_bounds__(512, 2) void vae_main(
    const float* __restrict__ x, const float* __restrict__ eps,
    const float* __restrict__ b_ee,
    const float* __restrict__ bih_f, const float* __restrict__ bhh_f,
    const float* __restrict__ bih_b, const float* __restrict__ bhh_b,
    const float* __restrict__ bih_d, const float* __restrict__ bhh_d,
    const float* __restrict__ b_enc, const float* __restrict__ b_z2h,
    const float* __restrict__ b_h2i, const float* __restrict__ b_ed,
    const float* __restrict__ b_dec,
    const char* __restrict__ ws, float* __restrict__ out)
{
  // G12 cols: [0,256)=r preact (ih+hh), [256,512)=z preact (ih+hh),
  //           [512,768)=in_ (ih only), [768,1024)=hn (hh only)
  __shared__ __align__(16) char G12[32 * RB_G];
  __shared__ __align__(16) char A1[2][32 * RB_A1];
  __shared__ __align__(16) char A2s[32 * RB_A2];
  __shared__ __align__(16) char HBs[32 * RB_A2];
  __shared__ __align__(16) char X0b[2][32 * RB_X];
  __shared__ __align__(16) char XCb[32 * RB_X];
  __shared__ float ST[32 * ST_W];

  const int tid = threadIdx.x;
  const int l = tid & 63;
  const int w = tid >> 6;
  const int c = l & 15;
  const int g4 = l >> 4;
  const int s0 = blockIdx.x * 32;

  const u16* PIHF = (const u16*)(ws + OFF_IHF);
  const u16* PHHF = (const u16*)(ws + OFF_HHF);
  const u16* PIHB = (const u16*)(ws + OFF_IHB);
  const u16* PIHD = (const u16*)(ws + OFF_IHD);
  const u16* PHHD = (const u16*)(ws + OFF_HHD);
  const u16* PENC = (const u16*)(ws + OFF_ENC);
  const u16* PZ2H = (const u16*)(ws + OFF_Z2H);
  const u16* PH2I = (const u16*)(ws + OFF_H2I);
  const u16* PDEC = (const u16*)(ws + OFF_DEC);
  const u16* PEE  = (const u16*)(ws + OFF_EE);
  const u16* PED  = (const u16*)(ws + OFF_ED);

  const int u_ = tid & 255;
  const int sh = tid >> 8;
  const float brf = bih_f[u_] + bhh_f[u_];
  const float bzf = bih_f[256 + u_] + bhh_f[256 + u_];
  const float binf = bih_f[512 + u_], bhnf = bhh_f[512 + u_];
  const float brb = bih_b[u_] + bhh_b[u_];
  const float bzb = bih_b[256 + u_] + bhh_b[256 + u_];
  const float binb = bih_b[512 + u_], bhnb = bhh_b[512 + u_];
  const float brd = bih_d[u_] + bhh_d[u_];
  const float bzd = bih_d[256 + u_] + bhh_d[256 + u_];
  const float bind = bih_d[512 + u_], bhnd = bhh_d[512 + u_];
  const float beer = b_ee[16 * w + c];
  const f32x4 zf = {0.f, 0.f, 0.f, 0.f};

  float hreg16[16];
  #pragma unroll
  for (int i = 0; i < 16; ++i) hreg16[i] = 0.f;

  // ---------------- prologue ----------------
  stage_x(x, s0, 0, X0b[0], tid);
  __syncthreads();
  {
    bf16x8 bE = *(const bf16x8*)(PEE + ((size_t)w * 64 + l) * 8);
    #pragma unroll
    for (int mt = 0; mt < 2; ++mt){
      bf16x8 a = ldF(X0b[0], mt * 16 + c, g4 * 8, RB_X);
      f32x4 xa = __builtin_amdgcn_mfma_f32_16x16x32_bf16(a, bE, zf, 0, 0, 0);
      #pragma unroll
      for (int q = 0; q < 4; ++q)
        stBf(A1[0], mt * 16 + g4 * 4 + q, 16 * w + c, RB_A1, fmaxf(xa[q] + beer, 0.f));
    }
  }
  for (int i = tid; i < 32 * RB_A2 / 4; i += 512) ((unsigned*)A2s)[i] = 0u;
  stage_x(x, s0, 1, X0b[1], tid);
  __syncthreads();

  // ---------------- encoder: 100 steps ----------------
  for (int t = 0; t < 100; ++t){
    bf16x8 a1f[4][2], a2f[8][2];
    #pragma unroll
    for (int kt = 0; kt < 4; ++kt)
      #pragma unroll
      for (int mt = 0; mt < 2; ++mt)
        a1f[kt][mt] = ldF(A1[t & 1], mt * 16 + c, kt * 32 + g4 * 8, RB_A1);
    #pragma unroll
    for (int kt = 0; kt < 8; ++kt)
      #pragma unroll
      for (int mt = 0; mt < 2; ++mt)
        a2f[kt][mt] = ldF(A2s, mt * 16 + c, kt * 32 + g4 * 8, RB_A2);

    #pragma unroll
    for (int j8 = 0; j8 < 8; ++j8){
      const int G = 8 * j8 + w;
      f32x4 acc0 = zf, acc1 = zf;
      if (G < 48){
        const int ntg = G;
        #pragma unroll
        for (int kt = 0; kt < 4; ++kt){
          bf16x8 b = *(const bf16x8*)(PIHF + ((size_t)(ntg * 4 + kt) * 64 + l) * 8);
          acc0 = __builtin_amdgcn_mfma_f32_16x16x32_bf16(a1f[kt][0], b, acc0, 0, 0, 0);
          acc1 = __builtin_amdgcn_mfma_f32_16x16x32_bf16(a1f[kt][1], b, acc1, 0, 0, 0);
        }
      }
      if (G < 32 || G >= 48){
        const int ntg = (G < 32) ? G : (G - 16);
        #pragma unroll
        for (int kt = 0; kt < 8; ++kt){
          bf16x8 b = *(const bf16x8*)(PHHF + ((size_t)(ntg * 8 + kt) * 64 + l) * 8);
          acc0 = __builtin_amdgcn_mfma_f32_16x16x32_bf16(a2f[kt][0], b, acc0, 0, 0, 0);
          acc1 = __builtin_amdgcn_mfma_f32_16x16x32_bf16(a2f[kt][1], b, acc1, 0, 0, 0);
        }
      }
      #pragma unroll
      for (int q = 0; q < 4; ++q){
        stBf(G12, g4 * 4 + q,      16 * G + c, RB_G, acc0[q]);
        stBf(G12, 16 + g4 * 4 + q, 16 * G + c, RB_G, acc1[q]);
      }
    }
    if (t < 99){
      bf16x8 bE = *(const bf16x8*)(PEE + ((size_t)w * 64 + l) * 8);
      #pragma unroll
      for (int mt = 0; mt < 2; ++mt){
        bf16x8 a = ldF(X0b[(t + 1) & 1], mt * 16 + c, g4 * 8, RB_X);
        f32x4 xa = __builtin_amdgcn_mfma_f32_16x16x32_bf16(a, bE, zf, 0, 0, 0);
        #pragma unroll
        for (int q = 0; q < 4; ++q)
          stBf(A1[(t + 1) & 1], mt * 16 + g4 * 4 + q, 16 * w + c, RB_A1, fmaxf(xa[q] + beer, 0.f));
      }
    }
    if (t < 98) stage_x(x, s0, t + 2, X0b[t & 1], tid);
    __syncthreads();

    #pragma unroll
    for (int i = 0; i < 16; ++i){
      const int s = sh * 16 + i;
      float gr  = ldBf1(G12, s, u_,        RB_G);
      float gz  = ldBf1(G12, s, 256 + u_,  RB_G);
      float gin = ldBf1(G12, s, 512 + u_,  RB_G);
      float ghn = ldBf1(G12, s, 768 + u_,  RB_G);
      float r = sigm(gr + brf);
      float zz = sigm(gz + bzf);
      float n = tanh_f(gin + binf + r * (ghn + bhnf));
      float h = (1.f - zz) * n + zz * hreg16[i];
      hreg16[i] = h;
      stBf(A2s, s, u_, RB_A2, h);
    }
    __syncthreads();
  }

  // ---------------- backward cell (h0=0) ----------------
  {
    bf16x8 a1f[4][2];
    #pragma unroll
    for (int kt = 0; kt < 4; ++kt)
      #pragma unroll
      for (int mt = 0; mt < 2; ++mt)
        a1f[kt][mt] = ldF(A1[1], mt * 16 + c, kt * 32 + g4 * 8, RB_A1);
    #pragma unroll
    for (int j8 = 0; j8 < 8; ++j8){
      const int G = 8 * j8 + w;
      if (G < 48){
        f32x4 acc0 = zf, acc1 = zf;
        #pragma unroll
        for (int kt = 0; kt < 4; ++kt){
          bf16x8 b = *(const bf16x8*)(PIHB + ((size_t)(G * 4 + kt) * 64 + l) * 8);
          acc0 = __builtin_amdgcn_mfma_f32_16x16x32_bf16(a1f[kt][0], b, acc0, 0, 0, 0);
          acc1 = __builtin_amdgcn_mfma_f32_16x16x32_bf16(a1f[kt][1], b, acc1, 0, 0, 0);
        }
        #pragma unroll
        for (int q = 0; q < 4; ++q){
          stBf(G12, g4 * 4 + q,      16 * G + c, RB_G, acc0[q]);
          stBf(G12, 16 + g4 * 4 + q, 16 * G + c, RB_G, acc1[q]);
        }
      }
    }
  }
  __syncthreads();
  {
    #pragma unroll
    for (int i = 0; i < 16; ++i){
      const int s = sh * 16 + i;
      float gr  = ldBf1(G12, s, u_,       RB_G);
      float gz  = ldBf1(G12, s, 256 + u_, RB_G);
      float gin = ldBf1(G12, s, 512 + u_, RB_G);
      float r = sigm(gr + brb);
      float zz = sigm(gz + bzb);
      float n = tanh_f(gin + binb + r * bhnb);
      stBf(HBs, s, u_, RB_A2, (1.f - zz) * n);
    }
  }
  __syncthreads();

  // ---------------- stats = [h_fwd | h_bwd] @ W_enc + b_enc ----------------
  {
    f32x4 sa[2] = {zf, zf};
    #pragma unroll
    for (int kt = 0; kt < 8; ++kt){
      bf16x8 b = *(const bf16x8*)(PENC + ((size_t)(w * 16 + kt) * 64 + l) * 8);
      #pragma unroll
      for (int mt = 0; mt < 2; ++mt){
        bf16x8 a = ldF(A2s, mt * 16 + c, kt * 32 + g4 * 8, RB_A2);
        sa[mt] = __builtin_amdgcn_mfma_f32_16x16x32_bf16(a, b, sa[mt], 0, 0, 0);
      }
    }
    #pragma unroll
    for (int kt = 8; kt < 16; ++kt){
      bf16x8 b = *(const bf16x8*)(PENC + ((size_t)(w * 16 + kt) * 64 + l) * 8);
      #pragma unroll
      for (int mt = 0; mt < 2; ++mt){
        bf16x8 a = ldF(HBs, mt * 16 + c, (kt - 8) * 32 + g4 * 8, RB_A2);
        sa[mt] = __builtin_amdgcn_mfma_f32_16x16x32_bf16(a, b, sa[mt], 0, 0, 0);
      }
    }
    const float be = b_enc[16 * w + c];
    #pragma unroll
    for (int mt = 0; mt < 2; ++mt)
      #pragma unroll
      for (int q = 0; q < 4; ++q)
        ST[(mt * 16 + g4 * 4 + q) * ST_W + 16 * w + c] = sa[mt][q] + be;
  }
  __syncthreads();

  // ---------------- z; write mu/logvar (f32) ----------------
  {
    const int s = tid >> 4, j0 = (tid & 15) * 4;
    #pragma unroll
    for (int i = 0; i < 4; ++i){
      const int j = j0 + i;
      float mu = ST[s * ST_W + j], lv = ST[s * ST_W + 64 + j];
      out[6553600u + (size_t)(s0 + s) * 64 + j] = mu;
      out[6684672u + (size_t)(s0 + s) * 64 + j] = lv;
      float zv = mu + __expf(0.5f * lv) * eps[(size_t)(s0 + s) * 64 + j];
      stBf(A1[0], s, j, RB_A1, zv);
    }
  }
  __syncthreads();

  // ---------------- h_dec0 = relu(z @ W_z2h + b_z2h) ----------------
  {
    #pragma unroll
    for (int nt = 0; nt < 2; ++nt){
      f32x4 da[2] = {zf, zf};
      #pragma unroll
      for (int kt = 0; kt < 2; ++kt){
        bf16x8 b = *(const bf16x8*)(PZ2H + ((size_t)((2 * w + nt) * 2 + kt) * 64 + l) * 8);
        #pragma unroll
        for (int mt = 0; mt < 2; ++mt){
          bf16x8 a = ldF(A1[0], mt * 16 + c, kt * 32 + g4 * 8, RB_A1);
          da[mt] = __builtin_amdgcn_mfma_f32_16x16x32_bf16(a, b, da[mt], 0, 0, 0);
        }
      }
      const int pcol = 32 * w + 16 * nt + c;
      const float bz = b_z2h[pcol];
      #pragma unroll
      for (int mt = 0; mt < 2; ++mt)
        #pragma unroll
        for (int q = 0; q < 4; ++q)
          stBf(A2s, mt * 16 + g4 * 4 + q, pcol, RB_A2, fmaxf(da[mt][q] + bz, 0.f));
    }
  }
  __syncthreads();

  // ---------------- hid0 (waves 2-5), cur0, hd preload ----------------
  float hd16[16];
  #pragma unroll
  for (int i = 0; i < 16; ++i) hd16[i] = ldBf1(A2s, sh * 16 + i, u_, RB_A2);

  if (w >= 2 && w < 6){
    const int iw = w - 2;
    f32x4 ha[2] = {zf, zf};
    #pragma unroll
    for (int kt = 0; kt < 8; ++kt){
      bf16x8 b = *(const bf16x8*)(PH2I + ((size_t)(iw * 8 + kt) * 64 + l) * 8);
      #pragma unroll
      for (int mt = 0; mt < 2; ++mt){
        bf16x8 a = ldF(A2s, mt * 16 + c, kt * 32 + g4 * 8, RB_A2);
        ha[mt] = __builtin_amdgcn_mfma_f32_16x16x32_bf16(a, b, ha[mt], 0, 0, 0);
      }
    }
    const float bh = b_h2i[16 * iw + c];
    #pragma unroll
    for (int mt = 0; mt < 2; ++mt)
      #pragma unroll
      for (int q = 0; q < 4; ++q)
        stBf(A1[0], mt * 16 + g4 * 4 + q, 64 + 16 * iw + c, RB_A1, fmaxf(ha[mt][q] + bh, 0.f));
  }
  {
    const int s = tid >> 4, c0 = (tid & 15) * 4;
    #pragma unroll
    for (int i = 0; i < 4; ++i)
      stBf(A1[0], s, c0 + i, RB_A1, fmaxf(b_ed[c0 + i], 0.f));
  }
  __syncthreads();

  const float bdecr = (w < 2) ? b_dec[16 * w + c] : 0.f;
  const float bh2ir = (w >= 2 && w < 6) ? b_h2i[16 * (w - 2) + c] : 0.f;
  const float bedr  = (w < 4) ? b_ed[16 * w + c] : 0.f;

  // ---------------- decoder: 100 steps ----------------
  for (int t = 0; t < 100; ++t){
    bf16x8 a1f[4][2], a2f[8][2];
    #pragma unroll
    for (int kt = 0; kt < 4; ++kt)
      #pragma unroll
      for (int mt = 0; mt < 2; ++mt)
        a1f[kt][mt] = ldF(A1[0], mt * 16 + c, kt * 32 + g4 * 8, RB_A1);
    #pragma unroll
    for (int kt = 0; kt < 8; ++kt)
      #pragma unroll
      for (int mt = 0; mt < 2; ++mt)
        a2f[kt][mt] = ldF(A2s, mt * 16 + c, kt * 32 + g4 * 8, RB_A2);

    #pragma unroll
    for (int j8 = 0; j8 < 8; ++j8){
      const int G = 8 * j8 + w;
      f32x4 acc0 = zf, acc1 = zf;
      if (G < 48){
        #pragma unroll
        for (int kt = 0; kt < 4; ++kt){
          bf16x8 b = *(const bf16x8*)(PIHD + ((size_t)(G * 4 + kt) * 64 + l) * 8);
          acc0 = __builtin_amdgcn_mfma_f32_16x16x32_bf16(a1f[kt][0], b, acc0, 0, 0, 0);
          acc1 = __builtin_amdgcn_mfma_f32_16x16x32_bf16(a1f[kt][1], b, acc1, 0, 0, 0);
        }
      }
      if (G < 32 || G >= 48){
        const int ntg = (G < 32) ? G : (G - 16);
        #pragma unroll
        for (int kt = 0; kt < 8; ++kt){
          bf16x8 b = *(const bf16x8*)(PHHD + ((size_t)(ntg * 8 + kt) * 64 + l) * 8);
          acc0 = __builtin_amdgcn_mfma_f32_16x16x32_bf16(a2f[kt][0], b, acc0, 0, 0, 0);
          acc1 = __builtin_amdgcn_mfma_f32_16x16x32_bf16(a2f[kt][1], b, acc1, 0, 0, 0);
        }
      }
      #pragma unroll
      for (int q = 0; q < 4; ++q){
        stBf(G12, g4 * 4 + q,      16 * G + c, RB_G, acc0[q]);
        stBf(G12, 16 + g4 * 4 + q, 16 * G + c, RB_G, acc1[q]);
      }
    }
    __syncthreads();

    #pragma unroll
    for (int i = 0; i < 16; ++i){
      const int s = sh * 16 + i;
      float gr  = ldBf1(G12, s, u_,       RB_G);
      float gz  = ldBf1(G12, s, 256 + u_, RB_G);
      float gin = ldBf1(G12, s, 512 + u_, RB_G);
      float ghn = ldBf1(G12, s, 768 + u_, RB_G);
      float r = sigm(gr + brd);
      float zz = sigm(gz + bzd);
      float n = tanh_f(gin + bind + r * (ghn + bhnd));
      float h = (1.f - zz) * n + zz * hd16[i];
      hd16[i] = h;
      stBf(A2s, s, u_, RB_A2, h);
    }
    __syncthreads();

    if (w < 2){
      f32x4 xc[2] = {zf, zf};
      #pragma unroll
      for (int kt = 0; kt < 8; ++kt){
        bf16x8 b = *(const bf16x8*)(PDEC + ((size_t)(w * 8 + kt) * 64 + l) * 8);
        #pragma unroll
        for (int mt = 0; mt < 2; ++mt){
          bf16x8 a = ldF(A2s, mt * 16 + c, kt * 32 + g4 * 8, RB_A2);
          xc[mt] = __builtin_amdgcn_mfma_f32_16x16x32_bf16(a, b, xc[mt], 0, 0, 0);
        }
      }
      #pragma unroll
      for (int mt = 0; mt < 2; ++mt)
        #pragma unroll
        for (int q = 0; q < 4; ++q){
          const int row = mt * 16 + g4 * 4 + q;
          const float v = xc[mt][q] + bdecr;
          out[(size_t)(s0 + row) * 3200 + t * 32 + 16 * w + c] = v;
          stBf(XCb, row, 16 * w + c, RB_X, v);
        }
    } else if (w < 6 && t < 99){
      const int iw = w - 2;
      f32x4 ha[2] = {zf, zf};
      #pragma unroll
      for (int kt = 0; kt < 8; ++kt){
        bf16x8 b = *(const bf16x8*)(PH2I + ((size_t)(iw * 8 + kt) * 64 + l) * 8);
        #pragma unroll
        for (int mt = 0; mt < 2; ++mt){
          bf16x8 a = ldF(A2s, mt * 16 + c, kt * 32 + g4 * 8, RB_A2);
          ha[mt] = __builtin_amdgcn_mfma_f32_16x16x32_bf16(a, b, ha[mt], 0, 0, 0);
        }
      }
      #pragma unroll
      for (int mt = 0; mt < 2; ++mt)
        #pragma unroll
        for (int q = 0; q < 4; ++q)
          stBf(A1[0], mt * 16 + g4 * 4 + q, 64 + 16 * iw + c, RB_A1, fmaxf(ha[mt][q] + bh2ir, 0.f));
    }
    __syncthreads();

    if (t < 99 && w < 4){
      bf16x8 b = *(const bf16x8*)(PED + ((size_t)w * 64 + l) * 8);
      #pragma unroll
      for (int mt = 0; mt < 2; ++mt){
        bf16x8 a = ldF(XCb, mt * 16 + c, g4 * 8, RB_X);
        f32x4 cu = __builtin_amdgcn_mfma_f32_16x16x32_bf16(a, b, zf, 0, 0, 0);
        #pragma unroll
        for (int q = 0; q < 4; ++q)
          stBf(A1[0], mt * 16 + g4 * 4 + q, 16 * w + c, RB_A1, fmaxf(cu[q] + bedr, 0.f));
      }
    }
    __syncthreads();
  }
}

extern "C" void kernel_launch(void* const* d_in, const int* in_sizes, int n_in,
                              void* d_out, int out_size, void* d_ws, size_t ws_size,
                              hipStream_t stream)
{
  (void)in_sizes; (void)n_in; (void)out_size;
  if (ws_size < (size_t)WS_TOTAL) return;

  const float* x    = (const float*)d_in[0];
  const float* eps  = (const float*)d_in[1];
  const float* Wee  = (const float*)d_in[2];
  const float* bee  = (const float*)d_in[3];
  const float* Wihf = (const float*)d_in[4];
  const float* Whhf = (const float*)d_in[5];
  const float* bihf = (const float*)d_in[6];
  const float* bhhf = (const float*)d_in[7];
  const float* Wihb = (const float*)d_in[8];
  const float* bihb = (const float*)d_in[10];
  const float* bhhb = (const float*)d_in[11];
  const float* Wenc = (const float*)d_in[12];
  const float* benc = (const float*)d_in[13];
  const float* Wz2h = (const float*)d_in[14];
  const float* bz2h = (const float*)d_in[15];
  const float* Wh2i = (const float*)d_in[16];
  const float* bh2i = (const float*)d_in[17];
  const float* Wihd = (const float*)d_in[18];
  const float* Whhd = (const float*)d_in[19];
  const float* bihd = (const float*)d_in[20];
  const float* bhhd = (const float*)d_in[21];
  const float* Wed  = (const float*)d_in[22];
  const float* bed  = (const float*)d_in[23];
  const float* Wdec = (const float*)d_in[24];
  const float* bdec = (const float*)d_in[25];
  char* ws = (char*)d_ws;

  pack_all<<<3128, 256, 0, stream>>>(Wihf, Whhf, Wihb, Wihd, Whhd, Wenc, Wz2h, Wh2i,
                                     Wdec, Wee, Wed, ws);
  vae_main<<<64, 512, 0, stream>>>(x, eps, bee, bihf, bhhf, bihb, bhhb, bihd, bhhd,
                                   benc, bz2h, bh2i, bed, bdec, ws, (float*)d_out);
}

// Round 7
// 2527.776 us; speedup vs baseline: 9.0793x; 2.3057x over previous
//
#include <hip/hip_runtime.h>
#include <hip/hip_bf16.h>

typedef __bf16 bf16x8 __attribute__((ext_vector_type(8)));
typedef float  f32x4  __attribute__((ext_vector_type(4)));
typedef unsigned short u16;

#define DEVI __device__ __forceinline__
#define MFMA __builtin_amdgcn_mfma_f32_16x16x32_bf16

DEVI u16 f2bf(float f){
  unsigned u = __builtin_bit_cast(unsigned, f);
  u += 0x7fffu + ((u >> 16) & 1u);
  return (u16)(u >> 16);
}
DEVI float bf2f(u16 h){
  unsigned u = ((unsigned)h) << 16;
  return __builtin_bit_cast(float, u);
}

// ---- ws layout (bytes); bf16 MFMA B-fragments, identity column order ----
enum : int {
  OFF_IHF = 0,                       // Wih_f: (128,768)  KT=4
  OFF_HHF = 196608,                  // Whh_f: (256,768)  KT=8
  OFF_IHB = 589824,                  // Wih_b: (128,768)  KT=4
  OFF_IHD = 786432,                  // Wih_d: (128,768)  KT=4
  OFF_HHD = 983040,                  // Whh_d: (256,768)  KT=8
  OFF_ENC = 1376256,                 // W_enc: (512,128)  KT=16
  OFF_Z2H = 1507328,                 // W_z2h: (64,256)   KT=2
  OFF_H2I = 1540096,                 // W_h2i: (256,64)   KT=8
  OFF_DEC = 1572864,                 // W_dec: (256,32)   KT=8
  OFF_EE  = 1589248,                 // W_ee : (32,128)   KT=1
  OFF_ED  = 1597440,                 // W_ed : (32,64)    KT=1 (unused by main, kept)
  OFF_DE  = 1601536,                 // Wde = Wdec@Wed: (256,64) KT=8
  OFF_BDE = 1634304,                 // bde = bdec@Wed + bed: 64 f32
  WS_TOTAL = 1634560
};

// fragment f = ntg*KT + kt covers cols [16*ntg,16*ntg+16), k in [kt*32,kt*32+32).
// lane l, elem j holds W[kt*32 + (l>>4)*8 + j][16*ntg + (l&15)].
DEVI void packseg(const float* __restrict__ W, u16* __restrict__ dst, int li, int N, int KT){
  int j = li & 7, l = (li >> 3) & 63, f = li >> 9;
  int kt = f % KT, ntg = f / KT;
  int k = kt * 32 + ((l >> 4) << 3) + j;
  int col = (ntg << 4) + (l & 15);
  dst[li] = f2bf(W[k * N + col]);
}

__global__ void pack_all(const float* Wihf, const float* Whhf, const float* Wihb,
                         const float* Wihd, const float* Whhd, const float* Wenc,
                         const float* Wz2h, const float* Wh2i, const float* Wdec,
                         const float* Wee,  const float* Wed,
                         const float* bed,  const float* bdec, char* ws)
{
  int idx = blockIdx.x * 256 + threadIdx.x;
  if (idx < 98304) { packseg(Wihf, (u16*)(ws+OFF_IHF), idx, 768, 4); return; } idx -= 98304;
  if (idx < 196608){ packseg(Whhf, (u16*)(ws+OFF_HHF), idx, 768, 8); return; } idx -= 196608;
  if (idx < 98304) { packseg(Wihb, (u16*)(ws+OFF_IHB), idx, 768, 4); return; } idx -= 98304;
  if (idx < 98304) { packseg(Wihd, (u16*)(ws+OFF_IHD), idx, 768, 4); return; } idx -= 98304;
  if (idx < 196608){ packseg(Whhd, (u16*)(ws+OFF_HHD), idx, 768, 8); return; } idx -= 196608;
  if (idx < 65536) { packseg(Wenc, (u16*)(ws+OFF_ENC), idx, 128, 16); return; } idx -= 65536;
  if (idx < 16384) { packseg(Wz2h, (u16*)(ws+OFF_Z2H), idx, 256, 2); return; } idx -= 16384;
  if (idx < 16384) { packseg(Wh2i, (u16*)(ws+OFF_H2I), idx, 64, 8); return; } idx -= 16384;
  if (idx < 8192)  { packseg(Wdec, (u16*)(ws+OFF_DEC), idx, 32, 8); return; } idx -= 8192;
  if (idx < 4096)  { packseg(Wee,  (u16*)(ws+OFF_EE),  idx, 128, 1); return; } idx -= 4096;
  if (idx < 2048)  { packseg(Wed,  (u16*)(ws+OFF_ED),  idx, 64, 1); return; } idx -= 2048;
  if (idx < 16384){
    // pack Wde = Wdec(256x32) @ Wed(32x64): N=64, KT=8
    int j = idx & 7, l = (idx >> 3) & 63, f = idx >> 9;
    int kt = f & 7, ntg = f >> 3;
    int k = kt * 32 + ((l >> 4) << 3) + j;
    int col = (ntg << 4) + (l & 15);
    float acc = 0.f;
    for (int m = 0; m < 32; ++m) acc += Wdec[k*32 + m] * Wed[m*64 + col];
    ((u16*)(ws+OFF_DE))[idx] = f2bf(acc);
    return;
  } idx -= 16384;
  if (idx < 64){
    float acc = bed[idx];
    for (int m = 0; m < 32; ++m) acc += bdec[m] * Wed[m*64 + idx];
    ((float*)(ws+OFF_BDE))[idx] = acc;
  }
}

// ---- LDS geometry (padded rows; G12T transposed [col][sample]) ----
enum : int { RB_A1 = 272, RB_A2 = 528, RB_X = 80, RB_GT = 40, ST_W = 132 };

DEVI bf16x8 ldF(const char* buf, int row, int kElem, int rowB){
  return *(const bf16x8*)(buf + row * rowB + kElem * 2);
}
DEVI void stBf(char* buf, int row, int col, int rowB, float v){
  *(u16*)(buf + row * rowB + col * 2) = f2bf(v);
}
DEVI float ldBf1(const char* buf, int row, int col, int rowB){
  return bf2f(*(const u16*)(buf + row * rowB + col * 2));
}
// G12T: store one D-fragment column (4 consecutive samples) as b64
DEVI void stG(char* g, int col, int g4, const f32x4& a){
  uint2 v;
  v.x = (unsigned)f2bf(a[0]) | ((unsigned)f2bf(a[1]) << 16);
  v.y = (unsigned)f2bf(a[2]) | ((unsigned)f2bf(a[3]) << 16);
  *(uint2*)(g + col * RB_GT + g4 * 8) = v;
}
DEVI void ldG4(const char* g, int col, int sq, float o[4]){
  uint2 v = *(const uint2*)(g + col * RB_GT + sq * 8);
  o[0] = bf2f((u16)(v.x & 0xffffu)); o[1] = bf2f((u16)(v.x >> 16));
  o[2] = bf2f((u16)(v.y & 0xffffu)); o[3] = bf2f((u16)(v.y >> 16));
}

DEVI float sigm(float x){ return 1.0f / (1.0f + __expf(-x)); }
DEVI float tanh_f(float x){ return 1.0f - 2.0f / (1.0f + __expf(2.0f * x)); }

// stage x[:, t, :] (16 samples x 32 dims) into Xb
DEVI void stage_x(const float* __restrict__ xg, int s0, int t, char* Xb, int tid){
  if (tid < 256){
    int s = tid >> 4, d0 = (tid & 15) * 2;
    float2 v = *(const float2*)(xg + (size_t)(s0 + s) * 3200 + t * 32 + d0);
    unsigned pk = (unsigned)f2bf(v.x) | ((unsigned)f2bf(v.y) << 16);
    *(unsigned*)(Xb + s * RB_X + d0 * 2) = pk;
  }
}

__global__ __launch_bounds__(1024, 1) void vae_main(
    const float* __restrict__ x, const float* __restrict__ eps,
    const float* __restrict__ b_ee,
    const float* __restrict__ bih_f, const float* __restrict__ bhh_f,
    const float* __restrict__ bih_b, const float* __restrict__ bhh_b,
    const float* __restrict__ bih_d, const float* __restrict__ bhh_d,
    const float* __restrict__ b_enc, const float* __restrict__ b_z2h,
    const float* __restrict__ b_h2i, const float* __restrict__ b_ed,
    const float* __restrict__ b_dec,
    const char* __restrict__ ws, float* __restrict__ out)
{
  // G12T cols: [0,256)=r (ih+hh), [256,512)=z (ih+hh), [512,768)=in_ (ih), [768,1024)=hn (hh)
  __shared__ __align__(16) char G12T[1024 * RB_GT];   // 40960
  __shared__ __align__(16) char A1[2][16 * RB_A1];    // 2 x 4352
  __shared__ __align__(16) char A2s[16 * RB_A2];      // 8448 (h, 256 cols bf16)
  __shared__ __align__(16) char HBs[16 * RB_A2];      // 8448 (h_bwd)
  __shared__ __align__(16) char X0b[2][16 * RB_X];    // 2 x 1280
  __shared__ float ST[16 * ST_W];                     // 8448

  const int tid = threadIdx.x;
  const int l = tid & 63;
  const int w = tid >> 6;       // wave 0..15
  const int c = l & 15;
  const int g4 = l >> 4;
  const int s0 = blockIdx.x * 16;

  const u16* PIHF = (const u16*)(ws + OFF_IHF);
  const u16* PHHF = (const u16*)(ws + OFF_HHF);
  const u16* PIHB = (const u16*)(ws + OFF_IHB);
  const u16* PIHD = (const u16*)(ws + OFF_IHD);
  const u16* PHHD = (const u16*)(ws + OFF_HHD);
  const u16* PENC = (const u16*)(ws + OFF_ENC);
  const u16* PZ2H = (const u16*)(ws + OFF_Z2H);
  const u16* PH2I = (const u16*)(ws + OFF_H2I);
  const u16* PDEC = (const u16*)(ws + OFF_DEC);
  const u16* PEE  = (const u16*)(ws + OFF_EE);
  const u16* PDE  = (const u16*)(ws + OFF_DE);

  const int u_ = tid & 255;     // hidden unit (combine phases)
  const int sq = tid >> 8;      // sample quarter (4 samples each)
  const float brf = bih_f[u_] + bhh_f[u_];
  const float bzf = bih_f[256 + u_] + bhh_f[256 + u_];
  const float binf = bih_f[512 + u_], bhnf = bhh_f[512 + u_];
  const float brb = bih_b[u_] + bhh_b[u_];
  const float bzb = bih_b[256 + u_] + bhh_b[256 + u_];
  const float binb = bih_b[512 + u_], bhnb = bhh_b[512 + u_];
  const float brd = bih_d[u_] + bhh_d[u_];
  const float bzd = bih_d[256 + u_] + bhh_d[256 + u_];
  const float bind = bih_d[512 + u_], bhnd = bhh_d[512 + u_];
  const float beer = b_ee[16 * (w & 7) + c];
  const f32x4 zf = {0.f, 0.f, 0.f, 0.f};

  // ---- gate weight fragments, STATIONARY IN REGISTERS (encoder set) ----
  // wave w owns units {w, w+16, w+32, w+48}:
  //   unit w     : ih(ntg=w)    + hh(ntg=w)      [r cols]
  //   unit w+16  : ih(ntg=w+16) + hh(ntg=w+16)   [z cols]
  //   unit w+32  : ih(ntg=w+32)                  [in_ cols]
  //   unit w+48  : hh(ntg=w+32)                  [hn cols]
  bf16x8 bIH[12], bHH[24];
  #pragma unroll
  for (int j = 0; j < 3; ++j){
    const int G = w + 16 * j;
    #pragma unroll
    for (int kt = 0; kt < 4; ++kt)
      bIH[j*4 + kt] = *(const bf16x8*)(PIHF + ((size_t)(G*4 + kt) * 64 + l) * 8);
  }
  #pragma unroll
  for (int j = 0; j < 2; ++j){
    const int ntg = w + 16 * j;
    #pragma unroll
    for (int kt = 0; kt < 8; ++kt)
      bHH[j*8 + kt] = *(const bf16x8*)(PHHF + ((size_t)(ntg*8 + kt) * 64 + l) * 8);
  }
  {
    const int ntg = w + 32;
    #pragma unroll
    for (int kt = 0; kt < 8; ++kt)
      bHH[16 + kt] = *(const bf16x8*)(PHHF + ((size_t)(ntg*8 + kt) * 64 + l) * 8);
  }
  const bf16x8 bEE = *(const bf16x8*)(PEE + ((size_t)(w & 7) * 64 + l) * 8);

  float hreg16[4];
  #pragma unroll
  for (int i = 0; i < 4; ++i) hreg16[i] = 0.f;

  // ---------------- prologue ----------------
  stage_x(x, s0, 0, X0b[0], tid);
  for (int i = tid; i < 16 * RB_A2 / 4; i += 1024) ((unsigned*)A2s)[i] = 0u;  // h0 = 0
  __syncthreads();
  if (w < 8){
    bf16x8 a = ldF(X0b[0], c, g4 * 8, RB_X);
    f32x4 xa = MFMA(a, bEE, zf, 0, 0, 0);
    #pragma unroll
    for (int q = 0; q < 4; ++q)
      stBf(A1[0], g4 * 4 + q, 16 * w + c, RB_A1, fmaxf(xa[q] + beer, 0.f));
  }
  stage_x(x, s0, 1, X0b[1], tid);
  __syncthreads();

  // ---------------- encoder: 100 steps ----------------
  for (int t = 0; t < 100; ++t){
    bf16x8 a1f[4], a2f[8];
    #pragma unroll
    for (int kt = 0; kt < 4; ++kt) a1f[kt] = ldF(A1[t & 1], c, kt * 32 + g4 * 8, RB_A1);
    #pragma unroll
    for (int kt = 0; kt < 8; ++kt) a2f[kt] = ldF(A2s, c, kt * 32 + g4 * 8, RB_A2);

    { // unit w (r): ih + hh
      f32x4 acc = zf;
      #pragma unroll
      for (int kt = 0; kt < 4; ++kt) acc = MFMA(a1f[kt], bIH[kt], acc, 0, 0, 0);
      #pragma unroll
      for (int kt = 0; kt < 8; ++kt) acc = MFMA(a2f[kt], bHH[kt], acc, 0, 0, 0);
      stG(G12T, 16 * w + c, g4, acc);
    }
    { // unit w+16 (z): ih + hh
      f32x4 acc = zf;
      #pragma unroll
      for (int kt = 0; kt < 4; ++kt) acc = MFMA(a1f[kt], bIH[4 + kt], acc, 0, 0, 0);
      #pragma unroll
      for (int kt = 0; kt < 8; ++kt) acc = MFMA(a2f[kt], bHH[8 + kt], acc, 0, 0, 0);
      stG(G12T, 16 * (w + 16) + c, g4, acc);
    }
    { // unit w+32 (in_): ih only
      f32x4 acc = zf;
      #pragma unroll
      for (int kt = 0; kt < 4; ++kt) acc = MFMA(a1f[kt], bIH[8 + kt], acc, 0, 0, 0);
      stG(G12T, 16 * (w + 32) + c, g4, acc);
    }
    { // unit w+48 (hn): hh only
      f32x4 acc = zf;
      #pragma unroll
      for (int kt = 0; kt < 8; ++kt) acc = MFMA(a2f[kt], bHH[16 + kt], acc, 0, 0, 0);
      stG(G12T, 16 * (w + 48) + c, g4, acc);
    }
    if (t < 99 && w < 8){
      bf16x8 a = ldF(X0b[(t + 1) & 1], c, g4 * 8, RB_X);
      f32x4 xa = MFMA(a, bEE, zf, 0, 0, 0);
      #pragma unroll
      for (int q = 0; q < 4; ++q)
        stBf(A1[(t + 1) & 1], g4 * 4 + q, 16 * w + c, RB_A1, fmaxf(xa[q] + beer, 0.f));
    }
    if (t < 98) stage_x(x, s0, t + 2, X0b[t & 1], tid);
    __syncthreads();

    { // combine: thread owns (unit u_, 4 samples)
      float gr[4], gz[4], gin[4], ghn[4];
      ldG4(G12T, u_,        sq, gr);
      ldG4(G12T, 256 + u_,  sq, gz);
      ldG4(G12T, 512 + u_,  sq, gin);
      ldG4(G12T, 768 + u_,  sq, ghn);
      #pragma unroll
      for (int i = 0; i < 4; ++i){
        float r  = sigm(gr[i] + brf);
        float zz = sigm(gz[i] + bzf);
        float n  = tanh_f(gin[i] + binf + r * (ghn[i] + bhnf));
        float h  = (1.f - zz) * n + zz * hreg16[i];
        hreg16[i] = h;
        stBf(A2s, sq * 4 + i, u_, RB_A2, h);
      }
    }
    __syncthreads();
  }

  // ---------------- backward cell (h0=0), gi from xe_99 (in A1[1]) ----------------
  {
    bf16x8 a1f[4];
    #pragma unroll
    for (int kt = 0; kt < 4; ++kt) a1f[kt] = ldF(A1[1], c, kt * 32 + g4 * 8, RB_A1);
    #pragma unroll
    for (int j = 0; j < 3; ++j){
      const int G = w + 16 * j;   // < 48
      f32x4 acc = zf;
      #pragma unroll
      for (int kt = 0; kt < 4; ++kt){
        bf16x8 b = *(const bf16x8*)(PIHB + ((size_t)(G*4 + kt) * 64 + l) * 8);
        acc = MFMA(a1f[kt], b, acc, 0, 0, 0);
      }
      stG(G12T, 16 * G + c, g4, acc);
    }
  }
  __syncthreads();
  {
    float gr[4], gz[4], gin[4];
    ldG4(G12T, u_,       sq, gr);
    ldG4(G12T, 256 + u_, sq, gz);
    ldG4(G12T, 512 + u_, sq, gin);
    #pragma unroll
    for (int i = 0; i < 4; ++i){
      float r  = sigm(gr[i] + brb);
      float zz = sigm(gz[i] + bzb);
      float n  = tanh_f(gin[i] + binb + r * bhnb);   // h0=0 => hn = bhh_b
      stBf(HBs, sq * 4 + i, u_, RB_A2, (1.f - zz) * n);
    }
  }
  __syncthreads();

  // ---------------- stats = [h_fwd | h_bwd] @ W_enc + b_enc ----------------
  if (w < 8){
    f32x4 sa = zf;
    #pragma unroll
    for (int kt = 0; kt < 8; ++kt){
      bf16x8 b = *(const bf16x8*)(PENC + ((size_t)(w*16 + kt) * 64 + l) * 8);
      sa = MFMA(ldF(A2s, c, kt * 32 + g4 * 8, RB_A2), b, sa, 0, 0, 0);
    }
    #pragma unroll
    for (int kt = 8; kt < 16; ++kt){
      bf16x8 b = *(const bf16x8*)(PENC + ((size_t)(w*16 + kt) * 64 + l) * 8);
      sa = MFMA(ldF(HBs, c, (kt - 8) * 32 + g4 * 8, RB_A2), b, sa, 0, 0, 0);
    }
    const float be = b_enc[16 * w + c];
    #pragma unroll
    for (int q = 0; q < 4; ++q)
      ST[(g4 * 4 + q) * ST_W + 16 * w + c] = sa[q] + be;
  }
  __syncthreads();

  // ---------------- z; write mu/logvar (f32) ----------------
  {
    const int s = tid >> 6, j = tid & 63;
    float mu = ST[s * ST_W + j], lv = ST[s * ST_W + 64 + j];
    out[6553600u + (size_t)(s0 + s) * 64 + j] = mu;
    out[6684672u + (size_t)(s0 + s) * 64 + j] = lv;
    float zv = mu + __expf(0.5f * lv) * eps[(size_t)(s0 + s) * 64 + j];
    stBf(A1[0], s, j, RB_A1, zv);
  }
  __syncthreads();

  // ---------------- h_dec0 = relu(z @ W_z2h + b_z2h) -> A2s ----------------
  {
    f32x4 da = zf;
    #pragma unroll
    for (int kt = 0; kt < 2; ++kt){
      bf16x8 b = *(const bf16x8*)(PZ2H + ((size_t)(w*2 + kt) * 64 + l) * 8);
      da = MFMA(ldF(A1[0], c, kt * 32 + g4 * 8, RB_A1), b, da, 0, 0, 0);
    }
    const float bz = b_z2h[16 * w + c];
    #pragma unroll
    for (int q = 0; q < 4; ++q)
      stBf(A2s, g4 * 4 + q, 16 * w + c, RB_A2, fmaxf(da[q] + bz, 0.f));
  }

  // ---- reload gate-B registers with DECODER weights; load head-B registers ----
  #pragma unroll
  for (int j = 0; j < 3; ++j){
    const int G = w + 16 * j;
    #pragma unroll
    for (int kt = 0; kt < 4; ++kt)
      bIH[j*4 + kt] = *(const bf16x8*)(PIHD + ((size_t)(G*4 + kt) * 64 + l) * 8);
  }
  #pragma unroll
  for (int j = 0; j < 2; ++j){
    const int ntg = w + 16 * j;
    #pragma unroll
    for (int kt = 0; kt < 8; ++kt)
      bHH[j*8 + kt] = *(const bf16x8*)(PHHD + ((size_t)(ntg*8 + kt) * 64 + l) * 8);
  }
  {
    const int ntg = w + 32;
    #pragma unroll
    for (int kt = 0; kt < 8; ++kt)
      bHH[16 + kt] = *(const bf16x8*)(PHHD + ((size_t)(ntg*8 + kt) * 64 + l) * 8);
  }
  bf16x8 bHD[8];
  {
    const u16* hb = (w < 4) ? PH2I : (w < 8) ? PDE : PDEC;
    const int g  = (w < 4) ? w : (w < 8) ? (w - 4) : (w & 1);
    #pragma unroll
    for (int kt = 0; kt < 8; ++kt)
      bHD[kt] = *(const bf16x8*)(hb + ((size_t)(g*8 + kt) * 64 + l) * 8);
  }
  __syncthreads();

  // ---------------- hid0 (waves 0-3), cur0 = relu(b_ed), hd preload ----------------
  float hd16[4];
  #pragma unroll
  for (int i = 0; i < 4; ++i) hd16[i] = ldBf1(A2s, sq * 4 + i, u_, RB_A2);

  if (w < 4){
    f32x4 ha = zf;
    #pragma unroll
    for (int kt = 0; kt < 8; ++kt)
      ha = MFMA(ldF(A2s, c, kt * 32 + g4 * 8, RB_A2), bHD[kt], ha, 0, 0, 0);
    const float bh = b_h2i[16 * w + c];
    #pragma unroll
    for (int q = 0; q < 4; ++q)
      stBf(A1[0], g4 * 4 + q, 64 + 16 * w + c, RB_A1, fmaxf(ha[q] + bh, 0.f));
  }
  {
    const int s = tid >> 6, j = tid & 63;
    stBf(A1[0], s, j, RB_A1, fmaxf(b_ed[j], 0.f));
  }
  __syncthreads();

  const float bh2ir = (w < 4) ? b_h2i[16 * w + c] : 0.f;
  const float bder  = (w >= 4 && w < 8) ? ((const float*)(ws + OFF_BDE))[16 * (w - 4) + c] : 0.f;
  const float bdecr = (w >= 8 && w < 10) ? b_dec[16 * (w - 8) + c] : 0.f;

  // ---------------- decoder: 100 steps ----------------
  for (int t = 0; t < 100; ++t){
    bf16x8 a1f[4], a2f[8];
    #pragma unroll
    for (int kt = 0; kt < 4; ++kt) a1f[kt] = ldF(A1[0], c, kt * 32 + g4 * 8, RB_A1);
    #pragma unroll
    for (int kt = 0; kt < 8; ++kt) a2f[kt] = ldF(A2s, c, kt * 32 + g4 * 8, RB_A2);

    {
      f32x4 acc = zf;
      #pragma unroll
      for (int kt = 0; kt < 4; ++kt) acc = MFMA(a1f[kt], bIH[kt], acc, 0, 0, 0);
      #pragma unroll
      for (int kt = 0; kt < 8; ++kt) acc = MFMA(a2f[kt], bHH[kt], acc, 0, 0, 0);
      stG(G12T, 16 * w + c, g4, acc);
    }
    {
      f32x4 acc = zf;
      #pragma unroll
      for (int kt = 0; kt < 4; ++kt) acc = MFMA(a1f[kt], bIH[4 + kt], acc, 0, 0, 0);
      #pragma unroll
      for (int kt = 0; kt < 8; ++kt) acc = MFMA(a2f[kt], bHH[8 + kt], acc, 0, 0, 0);
      stG(G12T, 16 * (w + 16) + c, g4, acc);
    }
    {
      f32x4 acc = zf;
      #pragma unroll
      for (int kt = 0; kt < 4; ++kt) acc = MFMA(a1f[kt], bIH[8 + kt], acc, 0, 0, 0);
      stG(G12T, 16 * (w + 32) + c, g4, acc);
    }
    {
      f32x4 acc = zf;
      #pragma unroll
      for (int kt = 0; kt < 8; ++kt) acc = MFMA(a2f[kt], bHH[16 + kt], acc, 0, 0, 0);
      stG(G12T, 16 * (w + 48) + c, g4, acc);
    }
    __syncthreads();

    {
      float gr[4], gz[4], gin[4], ghn[4];
      ldG4(G12T, u_,        sq, gr);
      ldG4(G12T, 256 + u_,  sq, gz);
      ldG4(G12T, 512 + u_,  sq, gin);
      ldG4(G12T, 768 + u_,  sq, ghn);
      #pragma unroll
      for (int i = 0; i < 4; ++i){
        float r  = sigm(gr[i] + brd);
        float zz = sigm(gz[i] + bzd);
        float n  = tanh_f(gin[i] + bind + r * (ghn[i] + bhnd));
        float h  = (1.f - zz) * n + zz * hd16[i];
        hd16[i] = h;
        stBf(A2s, sq * 4 + i, u_, RB_A2, h);
      }
    }
    __syncthreads();

    // heads: hid (w0-3) -> A1 hi; cur fused (w4-7) -> A1 lo; x_cur (w8-9) -> out
    if (w < 4){
      f32x4 ha = zf;
      #pragma unroll
      for (int kt = 0; kt < 8; ++kt)
        ha = MFMA(ldF(A2s, c, kt * 32 + g4 * 8, RB_A2), bHD[kt], ha, 0, 0, 0);
      #pragma unroll
      for (int q = 0; q < 4; ++q)
        stBf(A1[0], g4 * 4 + q, 64 + 16 * w + c, RB_A1, fmaxf(ha[q] + bh2ir, 0.f));
    } else if (w < 8){
      f32x4 cu = zf;
      #pragma unroll
      for (int kt = 0; kt < 8; ++kt)
        cu = MFMA(ldF(A2s, c, kt * 32 + g4 * 8, RB_A2), bHD[kt], cu, 0, 0, 0);
      #pragma unroll
      for (int q = 0; q < 4; ++q)
        stBf(A1[0], g4 * 4 + q, 16 * (w - 4) + c, RB_A1, fmaxf(cu[q] + bder, 0.f));
    } else if (w < 10){
      f32x4 xc = zf;
      #pragma unroll
      for (int kt = 0; kt < 8; ++kt)
        xc = MFMA(ldF(A2s, c, kt * 32 + g4 * 8, RB_A2), bHD[kt], xc, 0, 0, 0);
      #pragma unroll
      for (int q = 0; q < 4; ++q)
        out[(size_t)(s0 + g4 * 4 + q) * 3200 + t * 32 + 16 * (w - 8) + c] = xc[q] + bdecr;
    }
    __syncthreads();
  }
}

extern "C" void kernel_launch(void* const* d_in, const int* in_sizes, int n_in,
                              void* d_out, int out_size, void* d_ws, size_t ws_size,
                              hipStream_t stream)
{
  (void)in_sizes; (void)n_in; (void)out_size;
  if (ws_size < (size_t)WS_TOTAL) return;

  const float* x    = (const float*)d_in[0];
  const float* eps  = (const float*)d_in[1];
  const float* Wee  = (const float*)d_in[2];
  const float* bee  = (const float*)d_in[3];
  const float* Wihf = (const float*)d_in[4];
  const float* Whhf = (const float*)d_in[5];
  const float* bihf = (const float*)d_in[6];
  const float* bhhf = (const float*)d_in[7];
  const float* Wihb = (const float*)d_in[8];
  const float* bihb = (const float*)d_in[10];
  const float* bhhb = (const float*)d_in[11];
  const float* Wenc = (const float*)d_in[12];
  const float* benc = (const float*)d_in[13];
  const float* Wz2h = (const float*)d_in[14];
  const float* bz2h = (const float*)d_in[15];
  const float* Wh2i = (const float*)d_in[16];
  const float* bh2i = (const float*)d_in[17];
  const float* Wihd = (const float*)d_in[18];
  const float* Whhd = (const float*)d_in[19];
  const float* bihd = (const float*)d_in[20];
  const float* bhhd = (const float*)d_in[21];
  const float* Wed  = (const float*)d_in[22];
  const float* bed  = (const float*)d_in[23];
  const float* Wdec = (const float*)d_in[24];
  const float* bdec = (const float*)d_in[25];
  char* ws = (char*)d_ws;

  pack_all<<<3193, 256, 0, stream>>>(Wihf, Whhf, Wihb, Wihd, Whhd, Wenc, Wz2h, Wh2i,
                                     Wdec, Wee, Wed, bed, bdec, ws);
  vae_main<<<128, 1024, 0, stream>>>(x, eps, bee, bihf, bhhf, bihb, bhhb, bihd, bhhd,
                                     benc, bz2h, bh2i, bed, bdec, ws, (float*)d_out);
}

// Round 8
// 2162.859 us; speedup vs baseline: 10.6112x; 1.1687x over previous
//
#include <hip/hip_runtime.h>
#include <hip/hip_bf16.h>

typedef __bf16 bf16x8 __attribute__((ext_vector_type(8)));
typedef float  f32x4  __attribute__((ext_vector_type(4)));
typedef unsigned short u16;

#define DEVI __device__ __forceinline__
#define MFMA __builtin_amdgcn_mfma_f32_16x16x32_bf16

DEVI u16 f2bf(float f){
  unsigned u = __builtin_bit_cast(unsigned, f);
  u += 0x7fffu + ((u >> 16) & 1u);
  return (u16)(u >> 16);
}
DEVI float bf2f(u16 h){
  unsigned u = ((unsigned)h) << 16;
  return __builtin_bit_cast(float, u);
}

// ---- ws layout (bytes); bf16 MFMA B-fragments, identity column order ----
enum : int {
  OFF_IHF = 0,                       // Wih_f: (128,768)  KT=4
  OFF_HHF = 196608,                  // Whh_f: (256,768)  KT=8
  OFF_IHB = 589824,                  // Wih_b: (128,768)  KT=4
  OFF_IHD = 786432,                  // Wih_d: (128,768)  KT=4
  OFF_HHD = 983040,                  // Whh_d: (256,768)  KT=8
  OFF_ENC = 1376256,                 // W_enc: (512,128)  KT=16
  OFF_Z2H = 1507328,                 // W_z2h: (64,256)   KT=2
  OFF_H2I = 1540096,                 // W_h2i: (256,64)   KT=8
  OFF_DEC = 1572864,                 // W_dec: (256,32)   KT=8
  OFF_EE  = 1589248,                 // W_ee : (32,128)   KT=1
  OFF_ED  = 1597440,                 // W_ed : (32,64)    KT=1 (unused by main)
  OFF_DE  = 1601536,                 // Wde = Wdec@Wed: (256,64) KT=8
  OFF_BDE = 1634304,                 // bde = bdec@Wed + bed: 64 f32
  WS_TOTAL = 1634560
};

DEVI void packseg(const float* __restrict__ W, u16* __restrict__ dst, int li, int N, int KT){
  int j = li & 7, l = (li >> 3) & 63, f = li >> 9;
  int kt = f % KT, ntg = f / KT;
  int k = kt * 32 + ((l >> 4) << 3) + j;
  int col = (ntg << 4) + (l & 15);
  dst[li] = f2bf(W[k * N + col]);
}

__global__ void pack_all(const float* Wihf, const float* Whhf, const float* Wihb,
                         const float* Wihd, const float* Whhd, const float* Wenc,
                         const float* Wz2h, const float* Wh2i, const float* Wdec,
                         const float* Wee,  const float* Wed,
                         const float* bed,  const float* bdec, char* ws)
{
  int idx = blockIdx.x * 256 + threadIdx.x;
  if (idx < 98304) { packseg(Wihf, (u16*)(ws+OFF_IHF), idx, 768, 4); return; } idx -= 98304;
  if (idx < 196608){ packseg(Whhf, (u16*)(ws+OFF_HHF), idx, 768, 8); return; } idx -= 196608;
  if (idx < 98304) { packseg(Wihb, (u16*)(ws+OFF_IHB), idx, 768, 4); return; } idx -= 98304;
  if (idx < 98304) { packseg(Wihd, (u16*)(ws+OFF_IHD), idx, 768, 4); return; } idx -= 98304;
  if (idx < 196608){ packseg(Whhd, (u16*)(ws+OFF_HHD), idx, 768, 8); return; } idx -= 196608;
  if (idx < 65536) { packseg(Wenc, (u16*)(ws+OFF_ENC), idx, 128, 16); return; } idx -= 65536;
  if (idx < 16384) { packseg(Wz2h, (u16*)(ws+OFF_Z2H), idx, 256, 2); return; } idx -= 16384;
  if (idx < 16384) { packseg(Wh2i, (u16*)(ws+OFF_H2I), idx, 64, 8); return; } idx -= 16384;
  if (idx < 8192)  { packseg(Wdec, (u16*)(ws+OFF_DEC), idx, 32, 8); return; } idx -= 8192;
  if (idx < 4096)  { packseg(Wee,  (u16*)(ws+OFF_EE),  idx, 128, 1); return; } idx -= 4096;
  if (idx < 2048)  { packseg(Wed,  (u16*)(ws+OFF_ED),  idx, 64, 1); return; } idx -= 2048;
  if (idx < 16384){
    int j = idx & 7, l = (idx >> 3) & 63, f = idx >> 9;
    int kt = f & 7, ntg = f >> 3;
    int k = kt * 32 + ((l >> 4) << 3) + j;
    int col = (ntg << 4) + (l & 15);
    float acc = 0.f;
    for (int m = 0; m < 32; ++m) acc += Wdec[k*32 + m] * Wed[m*64 + col];
    ((u16*)(ws+OFF_DE))[idx] = f2bf(acc);
    return;
  } idx -= 16384;
  if (idx < 64){
    float acc = bed[idx];
    for (int m = 0; m < 32; ++m) acc += bdec[m] * Wed[m*64 + idx];
    ((float*)(ws+OFF_BDE))[idx] = acc;
  }
}

// ---- LDS geometry ----
enum : int { RB_A1 = 272, RB_A2 = 528, RB_X = 80 };

DEVI bf16x8 ldF(const char* buf, int row, int kElem, int rowB){
  return *(const bf16x8*)(buf + row * rowB + kElem * 2);
}
DEVI void stBf(char* buf, int row, int col, int rowB, float v){
  *(u16*)(buf + row * rowB + col * 2) = f2bf(v);
}
DEVI float ldBf1(const char* buf, int row, int col, int rowB){
  return bf2f(*(const u16*)(buf + row * rowB + col * 2));
}
DEVI bf16x8 gfrag(const u16* P, int ntg, int KT, int kt, int l){
  return *(const bf16x8*)(P + ((size_t)(ntg * KT + kt) * 64 + l) * 8);
}

// G12T: [1024 cols][16 samples bf16], 32 B rows, XOR-swizzled (bijective)
DEVI int gaddr(int col, int boff){
  int a = col * 32 + boff;
  return a ^ (((col >> 2) & 7) << 4);
}
DEVI void stG(char* g, int col, int g4, const f32x4& a){
  uint2 v;
  v.x = (unsigned)f2bf(a[0]) | ((unsigned)f2bf(a[1]) << 16);
  v.y = (unsigned)f2bf(a[2]) | ((unsigned)f2bf(a[3]) << 16);
  *(uint2*)(g + gaddr(col, g4 * 8)) = v;
}
DEVI void ldG8(const char* g, int col, int sh, float o[8]){
  uint4 v = *(const uint4*)(g + gaddr(col, sh * 16));
  o[0]=bf2f((u16)(v.x&0xffffu)); o[1]=bf2f((u16)(v.x>>16));
  o[2]=bf2f((u16)(v.y&0xffffu)); o[3]=bf2f((u16)(v.y>>16));
  o[4]=bf2f((u16)(v.z&0xffffu)); o[5]=bf2f((u16)(v.z>>16));
  o[6]=bf2f((u16)(v.w&0xffffu)); o[7]=bf2f((u16)(v.w>>16));
}

DEVI float sigm(float x){ return 1.0f / (1.0f + __expf(-x)); }
DEVI float tanh_f(float x){ return 1.0f - 2.0f / (1.0f + __expf(2.0f * x)); }

DEVI void stage_x(const float* __restrict__ xg, int s0, int t, char* Xb, int tid){
  if (tid < 256){
    int s = tid >> 4, d0 = (tid & 15) * 2;
    float2 v = *(const float2*)(xg + (size_t)(s0 + s) * 3200 + t * 32 + d0);
    unsigned pk = (unsigned)f2bf(v.x) | ((unsigned)f2bf(v.y) << 16);
    *(unsigned*)(Xb + s * RB_X + d0 * 2) = pk;
  }
}

// 128 blocks x 512 threads (8 waves), M=16 samples/block.
// Wave w owns gate groups G = w+8j: j=0,1 r | j=2,3 z | j=4,5 in | j=6,7 hn.
// Residency: r+in in VGPR (32 frags); enc: z-ih + hn0-kt0-3 in LDS (12); rest streamed.
// dec: LDS holds the 80 head fragments instead; all z/hn streamed.
__global__ __launch_bounds__(512, 2) void vae_main(
    const float* __restrict__ x, const float* __restrict__ eps,
    const float* __restrict__ b_ee,
    const float* __restrict__ bih_f, const float* __restrict__ bhh_f,
    const float* __restrict__ bih_b, const float* __restrict__ bhh_b,
    const float* __restrict__ bih_d, const float* __restrict__ bhh_d,
    const float* __restrict__ b_enc, const float* __restrict__ b_z2h,
    const float* __restrict__ b_h2i, const float* __restrict__ b_ed,
    const float* __restrict__ b_dec,
    const char* __restrict__ ws, float* __restrict__ out)
{
  __shared__ __align__(16) char G12T[1024 * 32];    // 32768, swizzled
  __shared__ __align__(16) char A1[2][16 * RB_A1];  // 8704
  __shared__ __align__(16) char A2s[16 * RB_A2];    // 8448
  __shared__ __align__(16) char X0b[2][16 * RB_X];  // 2560
  __shared__ __align__(16) char BL[98304];          // 96 x 1KB frag slots; aliases HBs/ST

  const int tid = threadIdx.x;
  const int l = tid & 63;
  const int w = tid >> 6;       // wave 0..7
  const int c = l & 15;
  const int g4 = l >> 4;
  const int s0 = blockIdx.x * 16;
  const int u_ = tid & 255;
  const int sh = tid >> 8;      // sample half (8 samples each)

  const u16* PIHF = (const u16*)(ws + OFF_IHF);
  const u16* PHHF = (const u16*)(ws + OFF_HHF);
  const u16* PIHB = (const u16*)(ws + OFF_IHB);
  const u16* PIHD = (const u16*)(ws + OFF_IHD);
  const u16* PHHD = (const u16*)(ws + OFF_HHD);
  const u16* PENC = (const u16*)(ws + OFF_ENC);
  const u16* PZ2H = (const u16*)(ws + OFF_Z2H);
  const u16* PH2I = (const u16*)(ws + OFF_H2I);
  const u16* PDEC = (const u16*)(ws + OFF_DEC);
  const u16* PEE  = (const u16*)(ws + OFF_EE);
  const u16* PDE  = (const u16*)(ws + OFF_DE);

  const f32x4 zf = {0.f, 0.f, 0.f, 0.f};
  char* wbl = BL + (size_t)w * 12 * 1024;   // this wave's enc gate-LDS slots

  // combine biases (phase-dependent: enc set now, dec set later)
  float brX = bih_f[u_] + bhh_f[u_];
  float bzX = bih_f[256 + u_] + bhh_f[256 + u_];
  float binX = bih_f[512 + u_], bhnX = bhh_f[512 + u_];
  const float beer = b_ee[16 * w + c];

  // ---- REG-resident gate weights: r-groups (w, w+8) full; in-groups ih ----
  bf16x8 bR[2][12], bI[2][4];
  #pragma unroll
  for (int j = 0; j < 2; ++j){
    #pragma unroll
    for (int kt = 0; kt < 4; ++kt) bR[j][kt]     = gfrag(PIHF, w + 8*j, 4, kt, l);
    #pragma unroll
    for (int kt = 0; kt < 8; ++kt) bR[j][4 + kt] = gfrag(PHHF, w + 8*j, 8, kt, l);
    #pragma unroll
    for (int kt = 0; kt < 4; ++kt) bI[j][kt]     = gfrag(PIHF, w + 32 + 8*j, 4, kt, l);
  }
  const bf16x8 bEE = gfrag(PEE, w, 1, 0, l);

  // ---- enc gate-LDS fill: slots 0-3 z2-ih, 4-7 z3-ih, 8-11 hn0-hh kt0-3 ----
  #pragma unroll
  for (int s = 0; s < 4; ++s) *(bf16x8*)(wbl + s*1024 + l*16)       = gfrag(PIHF, w + 16, 4, s, l);
  #pragma unroll
  for (int s = 0; s < 4; ++s) *(bf16x8*)(wbl + (4+s)*1024 + l*16)   = gfrag(PIHF, w + 24, 4, s, l);
  #pragma unroll
  for (int s = 0; s < 4; ++s) *(bf16x8*)(wbl + (8+s)*1024 + l*16)   = gfrag(PHHF, w + 32, 8, s, l);

  float hreg[8];
  #pragma unroll
  for (int i = 0; i < 8; ++i) hreg[i] = 0.f;

  // ---------------- prologue ----------------
  stage_x(x, s0, 0, X0b[0], tid);
  for (int i = tid; i < 16 * RB_A2 / 4; i += 512) ((unsigned*)A2s)[i] = 0u;
  __syncthreads();
  {
    bf16x8 a = ldF(X0b[0], c, g4 * 8, RB_X);
    f32x4 xa = MFMA(a, bEE, zf, 0, 0, 0);
    #pragma unroll
    for (int q = 0; q < 4; ++q)
      stBf(A1[0], g4 * 4 + q, 16 * w + c, RB_A1, fmaxf(xa[q] + beer, 0.f));
  }
  stage_x(x, s0, 1, X0b[1], tid);
  __syncthreads();

  // ---------------- encoder: 100 steps ----------------
  for (int t = 0; t < 100; ++t){
    bf16x8 a1f[4], a2f[8], sA[4], sB[4];
    #pragma unroll
    for (int kt = 0; kt < 4; ++kt) a1f[kt] = ldF(A1[t & 1], c, kt * 32 + g4 * 8, RB_A1);
    #pragma unroll
    for (int kt = 0; kt < 8; ++kt) a2f[kt] = ldF(A2s, c, kt * 32 + g4 * 8, RB_A2);

    // issue z2-hh stream
    #pragma unroll
    for (int q = 0; q < 4; ++q) sA[q] = gfrag(PHHF, w + 16, 8, q, l);
    #pragma unroll
    for (int q = 0; q < 4; ++q) sB[q] = gfrag(PHHF, w + 16, 8, 4 + q, l);

    f32x4 acc;
    // r0, r1 (REG)
    #pragma unroll
    for (int j = 0; j < 2; ++j){
      acc = zf;
      #pragma unroll
      for (int kt = 0; kt < 4; ++kt) acc = MFMA(a1f[kt], bR[j][kt], acc, 0, 0, 0);
      #pragma unroll
      for (int kt = 0; kt < 8; ++kt) acc = MFMA(a2f[kt], bR[j][4 + kt], acc, 0, 0, 0);
      stG(G12T, 16 * (w + 8*j) + c, g4, acc);
    }
    // in0, in1 (REG)
    #pragma unroll
    for (int j = 0; j < 2; ++j){
      acc = zf;
      #pragma unroll
      for (int kt = 0; kt < 4; ++kt) acc = MFMA(a1f[kt], bI[j][kt], acc, 0, 0, 0);
      stG(G12T, 16 * (w + 32 + 8*j) + c, g4, acc);
    }
    // z2 = ih(LDS 0-3) + hh(sA, sB)
    acc = zf;
    #pragma unroll
    for (int kt = 0; kt < 4; ++kt) acc = MFMA(a1f[kt], *(const bf16x8*)(wbl + kt*1024 + l*16), acc, 0, 0, 0);
    #pragma unroll
    for (int q = 0; q < 4; ++q) acc = MFMA(a2f[q], sA[q], acc, 0, 0, 0);
    #pragma unroll
    for (int q = 0; q < 4; ++q) acc = MFMA(a2f[4 + q], sB[q], acc, 0, 0, 0);
    stG(G12T, 16 * (w + 16) + c, g4, acc);
    // issue z3-hh
    #pragma unroll
    for (int q = 0; q < 4; ++q) sA[q] = gfrag(PHHF, w + 24, 8, q, l);
    #pragma unroll
    for (int q = 0; q < 4; ++q) sB[q] = gfrag(PHHF, w + 24, 8, 4 + q, l);
    // xe pipeline (covers stream latency)
    if (t < 99){
      bf16x8 a = ldF(X0b[(t + 1) & 1], c, g4 * 8, RB_X);
      f32x4 xa = MFMA(a, bEE, zf, 0, 0, 0);
      #pragma unroll
      for (int q = 0; q < 4; ++q)
        stBf(A1[(t + 1) & 1], g4 * 4 + q, 16 * w + c, RB_A1, fmaxf(xa[q] + beer, 0.f));
    }
    if (t < 98) stage_x(x, s0, t + 2, X0b[t & 1], tid);
    // z3 = ih(LDS 4-7) + hh(sA, sB)
    acc = zf;
    #pragma unroll
    for (int kt = 0; kt < 4; ++kt) acc = MFMA(a1f[kt], *(const bf16x8*)(wbl + (4+kt)*1024 + l*16), acc, 0, 0, 0);
    #pragma unroll
    for (int q = 0; q < 4; ++q) acc = MFMA(a2f[q], sA[q], acc, 0, 0, 0);
    #pragma unroll
    for (int q = 0; q < 4; ++q) acc = MFMA(a2f[4 + q], sB[q], acc, 0, 0, 0);
    stG(G12T, 16 * (w + 24) + c, g4, acc);
    // issue hn streams: sA = hn0 kt4-7, sB = hn1 kt0-3
    #pragma unroll
    for (int q = 0; q < 4; ++q) sA[q] = gfrag(PHHF, w + 32, 8, 4 + q, l);
    #pragma unroll
    for (int q = 0; q < 4; ++q) sB[q] = gfrag(PHHF, w + 40, 8, q, l);
    // hn0 = hh(LDS 8-11, kt0-3) + sA(kt4-7)
    acc = zf;
    #pragma unroll
    for (int q = 0; q < 4; ++q) acc = MFMA(a2f[q], *(const bf16x8*)(wbl + (8+q)*1024 + l*16), acc, 0, 0, 0);
    #pragma unroll
    for (int q = 0; q < 4; ++q) acc = MFMA(a2f[4 + q], sA[q], acc, 0, 0, 0);
    stG(G12T, 16 * (w + 48) + c, g4, acc);
    // hn1 = sB(kt0-3) + reloaded sA(kt4-7)
    #pragma unroll
    for (int q = 0; q < 4; ++q) sA[q] = gfrag(PHHF, w + 40, 8, 4 + q, l);
    acc = zf;
    #pragma unroll
    for (int q = 0; q < 4; ++q) acc = MFMA(a2f[q], sB[q], acc, 0, 0, 0);
    #pragma unroll
    for (int q = 0; q < 4; ++q) acc = MFMA(a2f[4 + q], sA[q], acc, 0, 0, 0);
    stG(G12T, 16 * (w + 56) + c, g4, acc);
    __syncthreads();

    // combine
    {
      float gr[8], gz[8], gi[8], gh[8];
      ldG8(G12T, u_,        sh, gr);
      ldG8(G12T, 256 + u_,  sh, gz);
      ldG8(G12T, 512 + u_,  sh, gi);
      ldG8(G12T, 768 + u_,  sh, gh);
      #pragma unroll
      for (int i = 0; i < 8; ++i){
        float r  = sigm(gr[i] + brX);
        float zz = sigm(gz[i] + bzX);
        float n  = tanh_f(gi[i] + binX + r * (gh[i] + bhnX));
        float h  = (1.f - zz) * n + zz * hreg[i];
        hreg[i] = h;
        stBf(A2s, sh * 8 + i, u_, RB_A2, h);
      }
    }
    __syncthreads();
  }

  // ---------------- backward cell (h0=0), gi from xe_99 in A1[1] ----------------
  {
    bf16x8 a1f[4];
    #pragma unroll
    for (int kt = 0; kt < 4; ++kt) a1f[kt] = ldF(A1[1], c, kt * 32 + g4 * 8, RB_A1);
    #pragma unroll
    for (int j = 0; j < 6; ++j){
      const int G = w + 8 * j;     // 0..47
      f32x4 acc = zf;
      #pragma unroll
      for (int kt = 0; kt < 4; ++kt) acc = MFMA(a1f[kt], gfrag(PIHB, G, 4, kt, l), acc, 0, 0, 0);
      stG(G12T, 16 * G + c, g4, acc);
    }
  }
  __syncthreads();
  { // combine_b -> HBs (aliased at BL, rows of RB_A2)
    const float brb = bih_b[u_] + bhh_b[u_];
    const float bzb = bih_b[256 + u_] + bhh_b[256 + u_];
    const float binb = bih_b[512 + u_], bhnb = bhh_b[512 + u_];
    float gr[8], gz[8], gi[8];
    ldG8(G12T, u_,       sh, gr);
    ldG8(G12T, 256 + u_, sh, gz);
    ldG8(G12T, 512 + u_, sh, gi);
    #pragma unroll
    for (int i = 0; i < 8; ++i){
      float r  = sigm(gr[i] + brb);
      float zz = sigm(gz[i] + bzb);
      float n  = tanh_f(gi[i] + binb + r * bhnb);
      stBf(BL, sh * 8 + i, u_, RB_A2, (1.f - zz) * n);
    }
  }
  __syncthreads();

  // ---------------- stats = [h_fwd | h_bwd] @ W_enc + b_enc -> ST (alias BL+8448) ----------------
  {
    f32x4 sa = zf;
    #pragma unroll
    for (int kt = 0; kt < 8; ++kt)
      sa = MFMA(ldF(A2s, c, kt * 32 + g4 * 8, RB_A2), gfrag(PENC, w, 16, kt, l), sa, 0, 0, 0);
    #pragma unroll
    for (int kt = 8; kt < 16; ++kt)
      sa = MFMA(ldF(BL, c, (kt - 8) * 32 + g4 * 8, RB_A2), gfrag(PENC, w, 16, kt, l), sa, 0, 0, 0);
    float* ST = (float*)(BL + 8448);
    const float be = b_enc[16 * w + c];
    #pragma unroll
    for (int q = 0; q < 4; ++q)
      ST[(g4 * 4 + q) * 132 + 16 * w + c] = sa[q] + be;
  }
  __syncthreads();

  // ---------------- z; write mu/logvar ----------------
  {
    const float* ST = (const float*)(BL + 8448);
    const int s = tid >> 5, jj = (tid & 31) * 2;
    #pragma unroll
    for (int d = 0; d < 2; ++d){
      const int j = jj + d;
      float mu = ST[s * 132 + j], lv = ST[s * 132 + 64 + j];
      out[6553600u + (size_t)(s0 + s) * 64 + j] = mu;
      out[6684672u + (size_t)(s0 + s) * 64 + j] = lv;
      float zv = mu + __expf(0.5f * lv) * eps[(size_t)(s0 + s) * 64 + j];
      stBf(A1[0], s, j, RB_A1, zv);
    }
  }
  __syncthreads();

  // ---------------- h_dec0; reload REG weights (dec); fill BL with heads ----------------
  {
    #pragma unroll
    for (int jj = 0; jj < 2; ++jj){
      const int g = w + 8 * jj;
      f32x4 da = zf;
      #pragma unroll
      for (int kt = 0; kt < 2; ++kt)
        da = MFMA(ldF(A1[0], c, kt * 32 + g4 * 8, RB_A1), gfrag(PZ2H, g, 2, kt, l), da, 0, 0, 0);
      const float bz = b_z2h[16 * g + c];
      #pragma unroll
      for (int q = 0; q < 4; ++q)
        stBf(A2s, g4 * 4 + q, 16 * g + c, RB_A2, fmaxf(da[q] + bz, 0.f));
    }
    // dec REG gate weights
    #pragma unroll
    for (int j = 0; j < 2; ++j){
      #pragma unroll
      for (int kt = 0; kt < 4; ++kt) bR[j][kt]     = gfrag(PIHD, w + 8*j, 4, kt, l);
      #pragma unroll
      for (int kt = 0; kt < 8; ++kt) bR[j][4 + kt] = gfrag(PHHD, w + 8*j, 8, kt, l);
      #pragma unroll
      for (int kt = 0; kt < 4; ++kt) bI[j][kt]     = gfrag(PIHD, w + 32 + 8*j, 4, kt, l);
    }
    // heads into BL: slots 0-31 h2i, 32-63 de, 64-79 dec
    #pragma unroll
    for (int s = 0; s < 10; ++s){
      const int S = w * 10 + s;
      const u16* P = (S < 32) ? PH2I : (S < 64) ? PDE : PDEC;
      const int fi = (S < 32) ? S : (S < 64) ? (S - 32) : (S - 64);
      *(bf16x8*)(BL + (size_t)S * 1024 + l * 16) =
        *(const bf16x8*)(P + ((size_t)fi * 64 + l) * 8);
    }
    // dec combine biases
    brX = bih_d[u_] + bhh_d[u_];
    bzX = bih_d[256 + u_] + bhh_d[256 + u_];
    binX = bih_d[512 + u_]; bhnX = bhh_d[512 + u_];
  }
  __syncthreads();

  const float bh2ir = (w < 4)  ? b_h2i[16 * w + c] : 0.f;
  const float bder  = (w >= 4) ? ((const float*)(ws + OFF_BDE))[16 * (w - 4) + c] : 0.f;
  const float bdecr = (w >= 6) ? b_dec[16 * (w - 6) + c] : 0.f;

  // ---------------- hid0, cur0, hd preload ----------------
  #pragma unroll
  for (int i = 0; i < 8; ++i) hreg[i] = ldBf1(A2s, sh * 8 + i, u_, RB_A2);
  if (w < 4){
    f32x4 ha = zf;
    #pragma unroll
    for (int kt = 0; kt < 8; ++kt)
      ha = MFMA(ldF(A2s, c, kt * 32 + g4 * 8, RB_A2),
                *(const bf16x8*)(BL + (size_t)(w * 8 + kt) * 1024 + l * 16), ha, 0, 0, 0);
    #pragma unroll
    for (int q = 0; q < 4; ++q)
      stBf(A1[0], g4 * 4 + q, 64 + 16 * w + c, RB_A1, fmaxf(ha[q] + bh2ir, 0.f));
  }
  {
    const int s = tid >> 5, jj = (tid & 31) * 2;
    #pragma unroll
    for (int d = 0; d < 2; ++d)
      stBf(A1[0], s, jj + d, RB_A1, fmaxf(b_ed[jj + d], 0.f));
  }
  __syncthreads();

  // ---------------- decoder: 100 steps ----------------
  for (int t = 0; t < 100; ++t){
    bf16x8 a1f[4], a2f[8], sA[4], sB[4];
    #pragma unroll
    for (int kt = 0; kt < 4; ++kt) a1f[kt] = ldF(A1[0], c, kt * 32 + g4 * 8, RB_A1);
    #pragma unroll
    for (int kt = 0; kt < 8; ++kt) a2f[kt] = ldF(A2s, c, kt * 32 + g4 * 8, RB_A2);

    // issue z2 streams: sA = z2-ih, sB = z2-hh kt0-3
    #pragma unroll
    for (int q = 0; q < 4; ++q) sA[q] = gfrag(PIHD, w + 16, 4, q, l);
    #pragma unroll
    for (int q = 0; q < 4; ++q) sB[q] = gfrag(PHHD, w + 16, 8, q, l);

    f32x4 acc;
    #pragma unroll
    for (int j = 0; j < 2; ++j){
      acc = zf;
      #pragma unroll
      for (int kt = 0; kt < 4; ++kt) acc = MFMA(a1f[kt], bR[j][kt], acc, 0, 0, 0);
      #pragma unroll
      for (int kt = 0; kt < 8; ++kt) acc = MFMA(a2f[kt], bR[j][4 + kt], acc, 0, 0, 0);
      stG(G12T, 16 * (w + 8*j) + c, g4, acc);
    }
    #pragma unroll
    for (int j = 0; j < 2; ++j){
      acc = zf;
      #pragma unroll
      for (int kt = 0; kt < 4; ++kt) acc = MFMA(a1f[kt], bI[j][kt], acc, 0, 0, 0);
      stG(G12T, 16 * (w + 32 + 8*j) + c, g4, acc);
    }
    // z2
    acc = zf;
    #pragma unroll
    for (int q = 0; q < 4; ++q) acc = MFMA(a1f[q], sA[q], acc, 0, 0, 0);
    #pragma unroll
    for (int q = 0; q < 4; ++q) acc = MFMA(a2f[q], sB[q], acc, 0, 0, 0);
    #pragma unroll
    for (int q = 0; q < 4; ++q) sA[q] = gfrag(PHHD, w + 16, 8, 4 + q, l);
    #pragma unroll
    for (int q = 0; q < 4; ++q) acc = MFMA(a2f[4 + q], sA[q], acc, 0, 0, 0);
    stG(G12T, 16 * (w + 16) + c, g4, acc);
    // z3
    #pragma unroll
    for (int q = 0; q < 4; ++q) sB[q] = gfrag(PIHD, w + 24, 4, q, l);
    #pragma unroll
    for (int q = 0; q < 4; ++q) sA[q] = gfrag(PHHD, w + 24, 8, q, l);
    acc = zf;
    #pragma unroll
    for (int q = 0; q < 4; ++q) acc = MFMA(a1f[q], sB[q], acc, 0, 0, 0);
    #pragma unroll
    for (int q = 0; q < 4; ++q) acc = MFMA(a2f[q], sA[q], acc, 0, 0, 0);
    #pragma unroll
    for (int q = 0; q < 4; ++q) sB[q] = gfrag(PHHD, w + 24, 8, 4 + q, l);
    #pragma unroll
    for (int q = 0; q < 4; ++q) acc = MFMA(a2f[4 + q], sB[q], acc, 0, 0, 0);
    stG(G12T, 16 * (w + 24) + c, g4, acc);
    // hn0
    #pragma unroll
    for (int q = 0; q < 4; ++q) sA[q] = gfrag(PHHD, w + 32, 8, q, l);
    #pragma unroll
    for (int q = 0; q < 4; ++q) sB[q] = gfrag(PHHD, w + 32, 8, 4 + q, l);
    acc = zf;
    #pragma unroll
    for (int q = 0; q < 4; ++q) acc = MFMA(a2f[q], sA[q], acc, 0, 0, 0);
    #pragma unroll
    for (int q = 0; q < 4; ++q) acc = MFMA(a2f[4 + q], sB[q], acc, 0, 0, 0);
    stG(G12T, 16 * (w + 48) + c, g4, acc);
    // hn1
    #pragma unroll
    for (int q = 0; q < 4; ++q) sA[q] = gfrag(PHHD, w + 40, 8, q, l);
    #pragma unroll
    for (int q = 0; q < 4; ++q) sB[q] = gfrag(PHHD, w + 40, 8, 4 + q, l);
    acc = zf;
    #pragma unroll
    for (int q = 0; q < 4; ++q) acc = MFMA(a2f[q], sA[q], acc, 0, 0, 0);
    #pragma unroll
    for (int q = 0; q < 4; ++q) acc = MFMA(a2f[4 + q], sB[q], acc, 0, 0, 0);
    stG(G12T, 16 * (w + 56) + c, g4, acc);
    __syncthreads();

    // combine -> h2
    {
      float gr[8], gz[8], gi[8], gh[8];
      ldG8(G12T, u_,        sh, gr);
      ldG8(G12T, 256 + u_,  sh, gz);
      ldG8(G12T, 512 + u_,  sh, gi);
      ldG8(G12T, 768 + u_,  sh, gh);
      #pragma unroll
      for (int i = 0; i < 8; ++i){
        float r  = sigm(gr[i] + brX);
        float zz = sigm(gz[i] + bzX);
        float n  = tanh_f(gi[i] + binX + r * (gh[i] + bhnX));
        float h  = (1.f - zz) * n + zz * hreg[i];
        hreg[i] = h;
        stBf(A2s, sh * 8 + i, u_, RB_A2, h);
      }
    }
    __syncthreads();

    // heads: w0-3 h2i -> A1 hi; w4-7 fused cur -> A1 lo; w6-7 also x_cur -> out
    {
      bf16x8 af[8];
      #pragma unroll
      for (int kt = 0; kt < 8; ++kt) af[kt] = ldF(A2s, c, kt * 32 + g4 * 8, RB_A2);
      const int hs = (w < 4) ? (w * 8) : (32 + (w - 4) * 8);
      f32x4 hv = zf;
      #pragma unroll
      for (int kt = 0; kt < 8; ++kt)
        hv = MFMA(af[kt], *(const bf16x8*)(BL + (size_t)(hs + kt) * 1024 + l * 16), hv, 0, 0, 0);
      if (w < 4){
        #pragma unroll
        for (int q = 0; q < 4; ++q)
          stBf(A1[0], g4 * 4 + q, 64 + 16 * w + c, RB_A1, fmaxf(hv[q] + bh2ir, 0.f));
      } else {
        #pragma unroll
        for (int q = 0; q < 4; ++q)
          stBf(A1[0], g4 * 4 + q, 16 * (w - 4) + c, RB_A1, fmaxf(hv[q] + bder, 0.f));
      }
      if (w >= 6){
        f32x4 xc = zf;
        #pragma unroll
        for (int kt = 0; kt < 8; ++kt)
          xc = MFMA(af[kt], *(const bf16x8*)(BL + (size_t)(64 + (w - 6) * 8 + kt) * 1024 + l * 16), xc, 0, 0, 0);
        #pragma unroll
        for (int q = 0; q < 4; ++q)
          out[(size_t)(s0 + g4 * 4 + q) * 3200 + t * 32 + 16 * (w - 6) + c] = xc[q] + bdecr;
      }
    }
    __syncthreads();
  }
}

extern "C" void kernel_launch(void* const* d_in, const int* in_sizes, int n_in,
                              void* d_out, int out_size, void* d_ws, size_t ws_size,
                              hipStream_t stream)
{
  (void)in_sizes; (void)n_in; (void)out_size;
  if (ws_size < (size_t)WS_TOTAL) return;

  const float* x    = (const float*)d_in[0];
  const float* eps  = (const float*)d_in[1];
  const float* Wee  = (const float*)d_in[2];
  const float* bee  = (const float*)d_in[3];
  const float* Wihf = (const float*)d_in[4];
  const float* Whhf = (const float*)d_in[5];
  const float* bihf = (const float*)d_in[6];
  const float* bhhf = (const float*)d_in[7];
  const float* Wihb = (const float*)d_in[8];
  const float* bihb = (const float*)d_in[10];
  const float* bhhb = (const float*)d_in[11];
  const float* Wenc = (const float*)d_in[12];
  const float* benc = (const float*)d_in[13];
  const float* Wz2h = (const float*)d_in[14];
  const float* bz2h = (const float*)d_in[15];
  const float* Wh2i = (const float*)d_in[16];
  const float* bh2i = (const float*)d_in[17];
  const float* Wihd = (const float*)d_in[18];
  const float* Whhd = (const float*)d_in[19];
  const float* bihd = (const float*)d_in[20];
  const float* bhhd = (const float*)d_in[21];
  const float* Wed  = (const float*)d_in[22];
  const float* bed  = (const float*)d_in[23];
  const float* Wdec = (const float*)d_in[24];
  const float* bdec = (const float*)d_in[25];
  char* ws = (char*)d_ws;

  pack_all<<<3193, 256, 0, stream>>>(Wihf, Whhf, Wihb, Wihd, Whhd, Wenc, Wz2h, Wh2i,
                                     Wdec, Wee, Wed, bed, bdec, ws);
  vae_main<<<128, 512, 0, stream>>>(x, eps, bee, bihf, bhhf, bihb, bhhb, bihd, bhhd,
                                    benc, bz2h, bh2i, bed, bdec, ws, (float*)d_out);
}

// Round 9
// 2125.029 us; speedup vs baseline: 10.8001x; 1.0178x over previous
//
#include <hip/hip_runtime.h>
#include <hip/hip_bf16.h>

typedef __bf16 bf16x8 __attribute__((ext_vector_type(8)));
typedef float  f32x4  __attribute__((ext_vector_type(4)));
typedef unsigned short u16;

#define DEVI __device__ __forceinline__
#define MFMA __builtin_amdgcn_mfma_f32_16x16x32_bf16

DEVI u16 f2bf(float f){
  unsigned u = __builtin_bit_cast(unsigned, f);
  u += 0x7fffu + ((u >> 16) & 1u);
  return (u16)(u >> 16);
}
DEVI float bf2f(u16 h){
  unsigned u = ((unsigned)h) << 16;
  return __builtin_bit_cast(float, u);
}

// ---- ws layout (bytes); bf16 MFMA B-fragments, identity column order ----
enum : int {
  OFF_IHF = 0,                       // Wih_f: (128,768)  KT=4
  OFF_HHF = 196608,                  // Whh_f: (256,768)  KT=8
  OFF_IHB = 589824,                  // Wih_b: (128,768)  KT=4
  OFF_IHD = 786432,                  // Wih_d: (128,768)  KT=4
  OFF_HHD = 983040,                  // Whh_d: (256,768)  KT=8
  OFF_ENC = 1376256,                 // W_enc: (512,128)  KT=16
  OFF_Z2H = 1507328,                 // W_z2h: (64,256)   KT=2
  OFF_H2I = 1540096,                 // W_h2i: (256,64)   KT=8
  OFF_DEC = 1572864,                 // W_dec: (256,32)   KT=8
  OFF_EE  = 1589248,                 // W_ee : (32,128)   KT=1
  OFF_ED  = 1597440,                 // W_ed : (32,64)    KT=1 (unused by main)
  OFF_DE  = 1601536,                 // Wde = Wdec@Wed: (256,64) KT=8
  OFF_BDE = 1634304,                 // bde = bdec@Wed + bed: 64 f32
  WS_TOTAL = 1634560
};

DEVI void packseg(const float* __restrict__ W, u16* __restrict__ dst, int li, int N, int KT){
  int j = li & 7, l = (li >> 3) & 63, f = li >> 9;
  int kt = f % KT, ntg = f / KT;
  int k = kt * 32 + ((l >> 4) << 3) + j;
  int col = (ntg << 4) + (l & 15);
  dst[li] = f2bf(W[k * N + col]);
}

__global__ void pack_all(const float* Wihf, const float* Whhf, const float* Wihb,
                         const float* Wihd, const float* Whhd, const float* Wenc,
                         const float* Wz2h, const float* Wh2i, const float* Wdec,
                         const float* Wee,  const float* Wed,
                         const float* bed,  const float* bdec, char* ws)
{
  int idx = blockIdx.x * 256 + threadIdx.x;
  if (idx < 98304) { packseg(Wihf, (u16*)(ws+OFF_IHF), idx, 768, 4); return; } idx -= 98304;
  if (idx < 196608){ packseg(Whhf, (u16*)(ws+OFF_HHF), idx, 768, 8); return; } idx -= 196608;
  if (idx < 98304) { packseg(Wihb, (u16*)(ws+OFF_IHB), idx, 768, 4); return; } idx -= 98304;
  if (idx < 98304) { packseg(Wihd, (u16*)(ws+OFF_IHD), idx, 768, 4); return; } idx -= 98304;
  if (idx < 196608){ packseg(Whhd, (u16*)(ws+OFF_HHD), idx, 768, 8); return; } idx -= 196608;
  if (idx < 65536) { packseg(Wenc, (u16*)(ws+OFF_ENC), idx, 128, 16); return; } idx -= 65536;
  if (idx < 16384) { packseg(Wz2h, (u16*)(ws+OFF_Z2H), idx, 256, 2); return; } idx -= 16384;
  if (idx < 16384) { packseg(Wh2i, (u16*)(ws+OFF_H2I), idx, 64, 8); return; } idx -= 16384;
  if (idx < 8192)  { packseg(Wdec, (u16*)(ws+OFF_DEC), idx, 32, 8); return; } idx -= 8192;
  if (idx < 4096)  { packseg(Wee,  (u16*)(ws+OFF_EE),  idx, 128, 1); return; } idx -= 4096;
  if (idx < 2048)  { packseg(Wed,  (u16*)(ws+OFF_ED),  idx, 64, 1); return; } idx -= 2048;
  if (idx < 16384){
    int j = idx & 7, l = (idx >> 3) & 63, f = idx >> 9;
    int kt = f & 7, ntg = f >> 3;
    int k = kt * 32 + ((l >> 4) << 3) + j;
    int col = (ntg << 4) + (l & 15);
    float acc = 0.f;
    for (int m = 0; m < 32; ++m) acc += Wdec[k*32 + m] * Wed[m*64 + col];
    ((u16*)(ws+OFF_DE))[idx] = f2bf(acc);
    return;
  } idx -= 16384;
  if (idx < 64){
    float acc = bed[idx];
    for (int m = 0; m < 32; ++m) acc += bdec[m] * Wed[m*64 + idx];
    ((float*)(ws+OFF_BDE))[idx] = acc;
  }
}

// ---- LDS geometry ----
enum : int { RB_A1 = 272, RB_A2 = 528, RB_X = 80 };

DEVI bf16x8 ldF(const char* buf, int row, int kElem, int rowB){
  return *(const bf16x8*)(buf + row * rowB + kElem * 2);
}
DEVI void stBf(char* buf, int row, int col, int rowB, float v){
  *(u16*)(buf + row * rowB + col * 2) = f2bf(v);
}
DEVI float ldBf1(const char* buf, int row, int col, int rowB){
  return bf2f(*(const u16*)(buf + row * rowB + col * 2));
}
DEVI bf16x8 gfrag(const u16* P, int ntg, int KT, int kt, int l){
  return *(const bf16x8*)(P + ((size_t)(ntg * KT + kt) * 64 + l) * 8);
}

// G12T: [1024 cols][16 samples bf16], 32 B rows, XOR-swizzled (bijective)
DEVI int gaddr(int col, int boff){
  int a = col * 32 + boff;
  return a ^ (((col >> 2) & 7) << 4);
}
DEVI void stG(char* g, int col, int g4, const f32x4& a){
  uint2 v;
  v.x = (unsigned)f2bf(a[0]) | ((unsigned)f2bf(a[1]) << 16);
  v.y = (unsigned)f2bf(a[2]) | ((unsigned)f2bf(a[3]) << 16);
  *(uint2*)(g + gaddr(col, g4 * 8)) = v;
}
DEVI void ldG8(const char* g, int col, int sh, float o[8]){
  uint4 v = *(const uint4*)(g + gaddr(col, sh * 16));
  o[0]=bf2f((u16)(v.x&0xffffu)); o[1]=bf2f((u16)(v.x>>16));
  o[2]=bf2f((u16)(v.y&0xffffu)); o[3]=bf2f((u16)(v.y>>16));
  o[4]=bf2f((u16)(v.z&0xffffu)); o[5]=bf2f((u16)(v.z>>16));
  o[6]=bf2f((u16)(v.w&0xffffu)); o[7]=bf2f((u16)(v.w>>16));
}

DEVI float sigm(float x){ return 1.0f / (1.0f + __expf(-x)); }
DEVI float tanh_f(float x){ return 1.0f - 2.0f / (1.0f + __expf(2.0f * x)); }

DEVI void stage_x(const float* __restrict__ xg, int s0, int t, char* Xb, int tid){
  if (tid < 256){
    int s = tid >> 4, d0 = (tid & 15) * 2;
    float2 v = *(const float2*)(xg + (size_t)(s0 + s) * 3200 + t * 32 + d0);
    unsigned pk = (unsigned)f2bf(v.x) | ((unsigned)f2bf(v.y) << 16);
    *(unsigned*)(Xb + s * RB_X + d0 * 2) = pk;
  }
}

// 128 blocks x 512 threads (8 waves), M=16 samples/block.
// Wave w owns gate groups G = w+8j: j=0,1 r | j=2,3 z | j=4,5 in | j=6,7 hn.
// Residency: r+in in VGPR (32 frags); enc: z-ih + hn0-kt0-3 in LDS (12); rest streamed.
// dec: LDS holds the 80 head fragments instead; all z/hn streamed.
// amdgpu_waves_per_eu(2,2): pin occupancy target to 2 waves/SIMD so the
// allocator may use the full 256 VGPRs (round-8 defaulted to 128 and spilled).
__global__ __launch_bounds__(512)
__attribute__((amdgpu_waves_per_eu(2, 2)))
void vae_main(
    const float* __restrict__ x, const float* __restrict__ eps,
    const float* __restrict__ b_ee,
    const float* __restrict__ bih_f, const float* __restrict__ bhh_f,
    const float* __restrict__ bih_b, const float* __restrict__ bhh_b,
    const float* __restrict__ bih_d, const float* __restrict__ bhh_d,
    const float* __restrict__ b_enc, const float* __restrict__ b_z2h,
    const float* __restrict__ b_h2i, const float* __restrict__ b_ed,
    const float* __restrict__ b_dec,
    const char* __restrict__ ws, float* __restrict__ out)
{
  __shared__ __align__(16) char G12T[1024 * 32];    // 32768, swizzled
  __shared__ __align__(16) char A1[2][16 * RB_A1];  // 8704
  __shared__ __align__(16) char A2s[16 * RB_A2];    // 8448
  __shared__ __align__(16) char X0b[2][16 * RB_X];  // 2560
  __shared__ __align__(16) char BL[98304];          // 96 x 1KB frag slots; aliases HBs/ST

  const int tid = threadIdx.x;
  const int l = tid & 63;
  const int w = tid >> 6;       // wave 0..7
  const int c = l & 15;
  const int g4 = l >> 4;
  const int s0 = blockIdx.x * 16;
  const int u_ = tid & 255;
  const int sh = tid >> 8;      // sample half (8 samples each)

  const u16* PIHF = (const u16*)(ws + OFF_IHF);
  const u16* PHHF = (const u16*)(ws + OFF_HHF);
  const u16* PIHB = (const u16*)(ws + OFF_IHB);
  const u16* PIHD = (const u16*)(ws + OFF_IHD);
  const u16* PHHD = (const u16*)(ws + OFF_HHD);
  const u16* PENC = (const u16*)(ws + OFF_ENC);
  const u16* PZ2H = (const u16*)(ws + OFF_Z2H);
  const u16* PH2I = (const u16*)(ws + OFF_H2I);
  const u16* PDEC = (const u16*)(ws + OFF_DEC);
  const u16* PEE  = (const u16*)(ws + OFF_EE);
  const u16* PDE  = (const u16*)(ws + OFF_DE);

  const f32x4 zf = {0.f, 0.f, 0.f, 0.f};
  char* wbl = BL + (size_t)w * 12 * 1024;   // this wave's enc gate-LDS slots

  // combine biases (phase-dependent: enc set now, dec set later)
  float brX = bih_f[u_] + bhh_f[u_];
  float bzX = bih_f[256 + u_] + bhh_f[256 + u_];
  float binX = bih_f[512 + u_], bhnX = bhh_f[512 + u_];
  const float beer = b_ee[16 * w + c];

  // ---- REG-resident gate weights: r-groups (w, w+8) full; in-groups ih ----
  bf16x8 bR[2][12], bI[2][4];
  #pragma unroll
  for (int j = 0; j < 2; ++j){
    #pragma unroll
    for (int kt = 0; kt < 4; ++kt) bR[j][kt]     = gfrag(PIHF, w + 8*j, 4, kt, l);
    #pragma unroll
    for (int kt = 0; kt < 8; ++kt) bR[j][4 + kt] = gfrag(PHHF, w + 8*j, 8, kt, l);
    #pragma unroll
    for (int kt = 0; kt < 4; ++kt) bI[j][kt]     = gfrag(PIHF, w + 32 + 8*j, 4, kt, l);
  }
  const bf16x8 bEE = gfrag(PEE, w, 1, 0, l);

  // ---- enc gate-LDS fill: slots 0-3 z2-ih, 4-7 z3-ih, 8-11 hn0-hh kt0-3 ----
  #pragma unroll
  for (int s = 0; s < 4; ++s) *(bf16x8*)(wbl + s*1024 + l*16)       = gfrag(PIHF, w + 16, 4, s, l);
  #pragma unroll
  for (int s = 0; s < 4; ++s) *(bf16x8*)(wbl + (4+s)*1024 + l*16)   = gfrag(PIHF, w + 24, 4, s, l);
  #pragma unroll
  for (int s = 0; s < 4; ++s) *(bf16x8*)(wbl + (8+s)*1024 + l*16)   = gfrag(PHHF, w + 32, 8, s, l);

  float hreg[8];
  #pragma unroll
  for (int i = 0; i < 8; ++i) hreg[i] = 0.f;

  // ---------------- prologue ----------------
  stage_x(x, s0, 0, X0b[0], tid);
  for (int i = tid; i < 16 * RB_A2 / 4; i += 512) ((unsigned*)A2s)[i] = 0u;
  __syncthreads();
  {
    bf16x8 a = ldF(X0b[0], c, g4 * 8, RB_X);
    f32x4 xa = MFMA(a, bEE, zf, 0, 0, 0);
    #pragma unroll
    for (int q = 0; q < 4; ++q)
      stBf(A1[0], g4 * 4 + q, 16 * w + c, RB_A1, fmaxf(xa[q] + beer, 0.f));
  }
  stage_x(x, s0, 1, X0b[1], tid);
  __syncthreads();

  // ---------------- encoder: 100 steps ----------------
  for (int t = 0; t < 100; ++t){
    bf16x8 a1f[4], a2f[8], sA[4], sB[4];
    #pragma unroll
    for (int kt = 0; kt < 4; ++kt) a1f[kt] = ldF(A1[t & 1], c, kt * 32 + g4 * 8, RB_A1);
    #pragma unroll
    for (int kt = 0; kt < 8; ++kt) a2f[kt] = ldF(A2s, c, kt * 32 + g4 * 8, RB_A2);

    // issue z2-hh stream
    #pragma unroll
    for (int q = 0; q < 4; ++q) sA[q] = gfrag(PHHF, w + 16, 8, q, l);
    #pragma unroll
    for (int q = 0; q < 4; ++q) sB[q] = gfrag(PHHF, w + 16, 8, 4 + q, l);

    f32x4 acc;
    // r0, r1 (REG)
    #pragma unroll
    for (int j = 0; j < 2; ++j){
      acc = zf;
      #pragma unroll
      for (int kt = 0; kt < 4; ++kt) acc = MFMA(a1f[kt], bR[j][kt], acc, 0, 0, 0);
      #pragma unroll
      for (int kt = 0; kt < 8; ++kt) acc = MFMA(a2f[kt], bR[j][4 + kt], acc, 0, 0, 0);
      stG(G12T, 16 * (w + 8*j) + c, g4, acc);
    }
    // in0, in1 (REG)
    #pragma unroll
    for (int j = 0; j < 2; ++j){
      acc = zf;
      #pragma unroll
      for (int kt = 0; kt < 4; ++kt) acc = MFMA(a1f[kt], bI[j][kt], acc, 0, 0, 0);
      stG(G12T, 16 * (w + 32 + 8*j) + c, g4, acc);
    }
    // z2 = ih(LDS 0-3) + hh(sA, sB)
    acc = zf;
    #pragma unroll
    for (int kt = 0; kt < 4; ++kt) acc = MFMA(a1f[kt], *(const bf16x8*)(wbl + kt*1024 + l*16), acc, 0, 0, 0);
    #pragma unroll
    for (int q = 0; q < 4; ++q) acc = MFMA(a2f[q], sA[q], acc, 0, 0, 0);
    #pragma unroll
    for (int q = 0; q < 4; ++q) acc = MFMA(a2f[4 + q], sB[q], acc, 0, 0, 0);
    stG(G12T, 16 * (w + 16) + c, g4, acc);
    // issue z3-hh
    #pragma unroll
    for (int q = 0; q < 4; ++q) sA[q] = gfrag(PHHF, w + 24, 8, q, l);
    #pragma unroll
    for (int q = 0; q < 4; ++q) sB[q] = gfrag(PHHF, w + 24, 8, 4 + q, l);
    // xe pipeline (covers stream latency)
    if (t < 99){
      bf16x8 a = ldF(X0b[(t + 1) & 1], c, g4 * 8, RB_X);
      f32x4 xa = MFMA(a, bEE, zf, 0, 0, 0);
      #pragma unroll
      for (int q = 0; q < 4; ++q)
        stBf(A1[(t + 1) & 1], g4 * 4 + q, 16 * w + c, RB_A1, fmaxf(xa[q] + beer, 0.f));
    }
    if (t < 98) stage_x(x, s0, t + 2, X0b[t & 1], tid);
    // z3 = ih(LDS 4-7) + hh(sA, sB)
    acc = zf;
    #pragma unroll
    for (int kt = 0; kt < 4; ++kt) acc = MFMA(a1f[kt], *(const bf16x8*)(wbl + (4+kt)*1024 + l*16), acc, 0, 0, 0);
    #pragma unroll
    for (int q = 0; q < 4; ++q) acc = MFMA(a2f[q], sA[q], acc, 0, 0, 0);
    #pragma unroll
    for (int q = 0; q < 4; ++q) acc = MFMA(a2f[4 + q], sB[q], acc, 0, 0, 0);
    stG(G12T, 16 * (w + 24) + c, g4, acc);
    // issue hn streams: sA = hn0 kt4-7, sB = hn1 kt0-3
    #pragma unroll
    for (int q = 0; q < 4; ++q) sA[q] = gfrag(PHHF, w + 32, 8, 4 + q, l);
    #pragma unroll
    for (int q = 0; q < 4; ++q) sB[q] = gfrag(PHHF, w + 40, 8, q, l);
    // hn0 = hh(LDS 8-11, kt0-3) + sA(kt4-7)
    acc = zf;
    #pragma unroll
    for (int q = 0; q < 4; ++q) acc = MFMA(a2f[q], *(const bf16x8*)(wbl + (8+q)*1024 + l*16), acc, 0, 0, 0);
    #pragma unroll
    for (int q = 0; q < 4; ++q) acc = MFMA(a2f[4 + q], sA[q], acc, 0, 0, 0);
    stG(G12T, 16 * (w + 48) + c, g4, acc);
    // hn1 = sB(kt0-3) + reloaded sA(kt4-7)
    #pragma unroll
    for (int q = 0; q < 4; ++q) sA[q] = gfrag(PHHF, w + 40, 8, 4 + q, l);
    acc = zf;
    #pragma unroll
    for (int q = 0; q < 4; ++q) acc = MFMA(a2f[q], sB[q], acc, 0, 0, 0);
    #pragma unroll
    for (int q = 0; q < 4; ++q) acc = MFMA(a2f[4 + q], sA[q], acc, 0, 0, 0);
    stG(G12T, 16 * (w + 56) + c, g4, acc);
    __syncthreads();

    // combine
    {
      float gr[8], gz[8], gi[8], gh[8];
      ldG8(G12T, u_,        sh, gr);
      ldG8(G12T, 256 + u_,  sh, gz);
      ldG8(G12T, 512 + u_,  sh, gi);
      ldG8(G12T, 768 + u_,  sh, gh);
      #pragma unroll
      for (int i = 0; i < 8; ++i){
        float r  = sigm(gr[i] + brX);
        float zz = sigm(gz[i] + bzX);
        float n  = tanh_f(gi[i] + binX + r * (gh[i] + bhnX));
        float h  = (1.f - zz) * n + zz * hreg[i];
        hreg[i] = h;
        stBf(A2s, sh * 8 + i, u_, RB_A2, h);
      }
    }
    __syncthreads();
  }

  // ---------------- backward cell (h0=0), gi from xe_99 in A1[1] ----------------
  {
    bf16x8 a1f[4];
    #pragma unroll
    for (int kt = 0; kt < 4; ++kt) a1f[kt] = ldF(A1[1], c, kt * 32 + g4 * 8, RB_A1);
    #pragma unroll
    for (int j = 0; j < 6; ++j){
      const int G = w + 8 * j;     // 0..47
      f32x4 acc = zf;
      #pragma unroll
      for (int kt = 0; kt < 4; ++kt) acc = MFMA(a1f[kt], gfrag(PIHB, G, 4, kt, l), acc, 0, 0, 0);
      stG(G12T, 16 * G + c, g4, acc);
    }
  }
  __syncthreads();
  { // combine_b -> HBs (aliased at BL, rows of RB_A2)
    const float brb = bih_b[u_] + bhh_b[u_];
    const float bzb = bih_b[256 + u_] + bhh_b[256 + u_];
    const float binb = bih_b[512 + u_], bhnb = bhh_b[512 + u_];
    float gr[8], gz[8], gi[8];
    ldG8(G12T, u_,       sh, gr);
    ldG8(G12T, 256 + u_, sh, gz);
    ldG8(G12T, 512 + u_, sh, gi);
    #pragma unroll
    for (int i = 0; i < 8; ++i){
      float r  = sigm(gr[i] + brb);
      float zz = sigm(gz[i] + bzb);
      float n  = tanh_f(gi[i] + binb + r * bhnb);
      stBf(BL, sh * 8 + i, u_, RB_A2, (1.f - zz) * n);
    }
  }
  __syncthreads();

  // ---------------- stats = [h_fwd | h_bwd] @ W_enc + b_enc -> ST (alias BL+8448) ----------------
  {
    f32x4 sa = zf;
    #pragma unroll
    for (int kt = 0; kt < 8; ++kt)
      sa = MFMA(ldF(A2s, c, kt * 32 + g4 * 8, RB_A2), gfrag(PENC, w, 16, kt, l), sa, 0, 0, 0);
    #pragma unroll
    for (int kt = 8; kt < 16; ++kt)
      sa = MFMA(ldF(BL, c, (kt - 8) * 32 + g4 * 8, RB_A2), gfrag(PENC, w, 16, kt, l), sa, 0, 0, 0);
    float* ST = (float*)(BL + 8448);
    const float be = b_enc[16 * w + c];
    #pragma unroll
    for (int q = 0; q < 4; ++q)
      ST[(g4 * 4 + q) * 132 + 16 * w + c] = sa[q] + be;
  }
  __syncthreads();

  // ---------------- z; write mu/logvar ----------------
  {
    const float* ST = (const float*)(BL + 8448);
    const int s = tid >> 5, jj = (tid & 31) * 2;
    #pragma unroll
    for (int d = 0; d < 2; ++d){
      const int j = jj + d;
      float mu = ST[s * 132 + j], lv = ST[s * 132 + 64 + j];
      out[6553600u + (size_t)(s0 + s) * 64 + j] = mu;
      out[6684672u + (size_t)(s0 + s) * 64 + j] = lv;
      float zv = mu + __expf(0.5f * lv) * eps[(size_t)(s0 + s) * 64 + j];
      stBf(A1[0], s, j, RB_A1, zv);
    }
  }
  __syncthreads();

  // ---------------- h_dec0; reload REG weights (dec); fill BL with heads ----------------
  {
    #pragma unroll
    for (int jj = 0; jj < 2; ++jj){
      const int g = w + 8 * jj;
      f32x4 da = zf;
      #pragma unroll
      for (int kt = 0; kt < 2; ++kt)
        da = MFMA(ldF(A1[0], c, kt * 32 + g4 * 8, RB_A1), gfrag(PZ2H, g, 2, kt, l), da, 0, 0, 0);
      const float bz = b_z2h[16 * g + c];
      #pragma unroll
      for (int q = 0; q < 4; ++q)
        stBf(A2s, g4 * 4 + q, 16 * g + c, RB_A2, fmaxf(da[q] + bz, 0.f));
    }
    // dec REG gate weights
    #pragma unroll
    for (int j = 0; j < 2; ++j){
      #pragma unroll
      for (int kt = 0; kt < 4; ++kt) bR[j][kt]     = gfrag(PIHD, w + 8*j, 4, kt, l);
      #pragma unroll
      for (int kt = 0; kt < 8; ++kt) bR[j][4 + kt] = gfrag(PHHD, w + 8*j, 8, kt, l);
      #pragma unroll
      for (int kt = 0; kt < 4; ++kt) bI[j][kt]     = gfrag(PIHD, w + 32 + 8*j, 4, kt, l);
    }
    // heads into BL: slots 0-31 h2i, 32-63 de, 64-79 dec
    #pragma unroll
    for (int s = 0; s < 10; ++s){
      const int S = w * 10 + s;
      const u16* P = (S < 32) ? PH2I : (S < 64) ? PDE : PDEC;
      const int fi = (S < 32) ? S : (S < 64) ? (S - 32) : (S - 64);
      *(bf16x8*)(BL + (size_t)S * 1024 + l * 16) =
        *(const bf16x8*)(P + ((size_t)fi * 64 + l) * 8);
    }
    // dec combine biases
    brX = bih_d[u_] + bhh_d[u_];
    bzX = bih_d[256 + u_] + bhh_d[256 + u_];
    binX = bih_d[512 + u_]; bhnX = bhh_d[512 + u_];
  }
  __syncthreads();

  const float bh2ir = (w < 4)  ? b_h2i[16 * w + c] : 0.f;
  const float bder  = (w >= 4) ? ((const float*)(ws + OFF_BDE))[16 * (w - 4) + c] : 0.f;
  const float bdecr = (w >= 6) ? b_dec[16 * (w - 6) + c] : 0.f;

  // ---------------- hid0, cur0, hd preload ----------------
  #pragma unroll
  for (int i = 0; i < 8; ++i) hreg[i] = ldBf1(A2s, sh * 8 + i, u_, RB_A2);
  if (w < 4){
    f32x4 ha = zf;
    #pragma unroll
    for (int kt = 0; kt < 8; ++kt)
      ha = MFMA(ldF(A2s, c, kt * 32 + g4 * 8, RB_A2),
                *(const bf16x8*)(BL + (size_t)(w * 8 + kt) * 1024 + l * 16), ha, 0, 0, 0);
    #pragma unroll
    for (int q = 0; q < 4; ++q)
      stBf(A1[0], g4 * 4 + q, 64 + 16 * w + c, RB_A1, fmaxf(ha[q] + bh2ir, 0.f));
  }
  {
    const int s = tid >> 5, jj = (tid & 31) * 2;
    #pragma unroll
    for (int d = 0; d < 2; ++d)
      stBf(A1[0], s, jj + d, RB_A1, fmaxf(b_ed[jj + d], 0.f));
  }
  __syncthreads();

  // ---------------- decoder: 100 steps ----------------
  for (int t = 0; t < 100; ++t){
    bf16x8 a1f[4], a2f[8], sA[4], sB[4];
    #pragma unroll
    for (int kt = 0; kt < 4; ++kt) a1f[kt] = ldF(A1[0], c, kt * 32 + g4 * 8, RB_A1);
    #pragma unroll
    for (int kt = 0; kt < 8; ++kt) a2f[kt] = ldF(A2s, c, kt * 32 + g4 * 8, RB_A2);

    // issue z2 streams: sA = z2-ih, sB = z2-hh kt0-3
    #pragma unroll
    for (int q = 0; q < 4; ++q) sA[q] = gfrag(PIHD, w + 16, 4, q, l);
    #pragma unroll
    for (int q = 0; q < 4; ++q) sB[q] = gfrag(PHHD, w + 16, 8, q, l);

    f32x4 acc;
    #pragma unroll
    for (int j = 0; j < 2; ++j){
      acc = zf;
      #pragma unroll
      for (int kt = 0; kt < 4; ++kt) acc = MFMA(a1f[kt], bR[j][kt], acc, 0, 0, 0);
      #pragma unroll
      for (int kt = 0; kt < 8; ++kt) acc = MFMA(a2f[kt], bR[j][4 + kt], acc, 0, 0, 0);
      stG(G12T, 16 * (w + 8*j) + c, g4, acc);
    }
    #pragma unroll
    for (int j = 0; j < 2; ++j){
      acc = zf;
      #pragma unroll
      for (int kt = 0; kt < 4; ++kt) acc = MFMA(a1f[kt], bI[j][kt], acc, 0, 0, 0);
      stG(G12T, 16 * (w + 32 + 8*j) + c, g4, acc);
    }
    // z2
    acc = zf;
    #pragma unroll
    for (int q = 0; q < 4; ++q) acc = MFMA(a1f[q], sA[q], acc, 0, 0, 0);
    #pragma unroll
    for (int q = 0; q < 4; ++q) acc = MFMA(a2f[q], sB[q], acc, 0, 0, 0);
    #pragma unroll
    for (int q = 0; q < 4; ++q) sA[q] = gfrag(PHHD, w + 16, 8, 4 + q, l);
    #pragma unroll
    for (int q = 0; q < 4; ++q) acc = MFMA(a2f[4 + q], sA[q], acc, 0, 0, 0);
    stG(G12T, 16 * (w + 16) + c, g4, acc);
    // z3
    #pragma unroll
    for (int q = 0; q < 4; ++q) sB[q] = gfrag(PIHD, w + 24, 4, q, l);
    #pragma unroll
    for (int q = 0; q < 4; ++q) sA[q] = gfrag(PHHD, w + 24, 8, q, l);
    acc = zf;
    #pragma unroll
    for (int q = 0; q < 4; ++q) acc = MFMA(a1f[q], sB[q], acc, 0, 0, 0);
    #pragma unroll
    for (int q = 0; q < 4; ++q) acc = MFMA(a2f[q], sA[q], acc, 0, 0, 0);
    #pragma unroll
    for (int q = 0; q < 4; ++q) sB[q] = gfrag(PHHD, w + 24, 8, 4 + q, l);
    #pragma unroll
    for (int q = 0; q < 4; ++q) acc = MFMA(a2f[4 + q], sB[q], acc, 0, 0, 0);
    stG(G12T, 16 * (w + 24) + c, g4, acc);
    // hn0
    #pragma unroll
    for (int q = 0; q < 4; ++q) sA[q] = gfrag(PHHD, w + 32, 8, q, l);
    #pragma unroll
    for (int q = 0; q < 4; ++q) sB[q] = gfrag(PHHD, w + 32, 8, 4 + q, l);
    acc = zf;
    #pragma unroll
    for (int q = 0; q < 4; ++q) acc = MFMA(a2f[q], sA[q], acc, 0, 0, 0);
    #pragma unroll
    for (int q = 0; q < 4; ++q) acc = MFMA(a2f[4 + q], sB[q], acc, 0, 0, 0);
    stG(G12T, 16 * (w + 48) + c, g4, acc);
    // hn1
    #pragma unroll
    for (int q = 0; q < 4; ++q) sA[q] = gfrag(PHHD, w + 40, 8, q, l);
    #pragma unroll
    for (int q = 0; q < 4; ++q) sB[q] = gfrag(PHHD, w + 40, 8, 4 + q, l);
    acc = zf;
    #pragma unroll
    for (int q = 0; q < 4; ++q) acc = MFMA(a2f[q], sA[q], acc, 0, 0, 0);
    #pragma unroll
    for (int q = 0; q < 4; ++q) acc = MFMA(a2f[4 + q], sB[q], acc, 0, 0, 0);
    stG(G12T, 16 * (w + 56) + c, g4, acc);
    __syncthreads();

    // combine -> h2
    {
      float gr[8], gz[8], gi[8], gh[8];
      ldG8(G12T, u_,        sh, gr);
      ldG8(G12T, 256 + u_,  sh, gz);
      ldG8(G12T, 512 + u_,  sh, gi);
      ldG8(G12T, 768 + u_,  sh, gh);
      #pragma unroll
      for (int i = 0; i < 8; ++i){
        float r  = sigm(gr[i] + brX);
        float zz = sigm(gz[i] + bzX);
        float n  = tanh_f(gi[i] + binX + r * (gh[i] + bhnX));
        float h  = (1.f - zz) * n + zz * hreg[i];
        hreg[i] = h;
        stBf(A2s, sh * 8 + i, u_, RB_A2, h);
      }
    }
    __syncthreads();

    // heads: w0-3 h2i -> A1 hi; w4-7 fused cur -> A1 lo; w6-7 also x_cur -> out
    {
      bf16x8 af[8];
      #pragma unroll
      for (int kt = 0; kt < 8; ++kt) af[kt] = ldF(A2s, c, kt * 32 + g4 * 8, RB_A2);
      const int hs = (w < 4) ? (w * 8) : (32 + (w - 4) * 8);
      f32x4 hv = zf;
      #pragma unroll
      for (int kt = 0; kt < 8; ++kt)
        hv = MFMA(af[kt], *(const bf16x8*)(BL + (size_t)(hs + kt) * 1024 + l * 16), hv, 0, 0, 0);
      if (w < 4){
        #pragma unroll
        for (int q = 0; q < 4; ++q)
          stBf(A1[0], g4 * 4 + q, 64 + 16 * w + c, RB_A1, fmaxf(hv[q] + bh2ir, 0.f));
      } else {
        #pragma unroll
        for (int q = 0; q < 4; ++q)
          stBf(A1[0], g4 * 4 + q, 16 * (w - 4) + c, RB_A1, fmaxf(hv[q] + bder, 0.f));
      }
      if (w >= 6){
        f32x4 xc = zf;
        #pragma unroll
        for (int kt = 0; kt < 8; ++kt)
          xc = MFMA(af[kt], *(const bf16x8*)(BL + (size_t)(64 + (w - 6) * 8 + kt) * 1024 + l * 16), xc, 0, 0, 0);
        #pragma unroll
        for (int q = 0; q < 4; ++q)
          out[(size_t)(s0 + g4 * 4 + q) * 3200 + t * 32 + 16 * (w - 6) + c] = xc[q] + bdecr;
      }
    }
    __syncthreads();
  }
}

extern "C" void kernel_launch(void* const* d_in, const int* in_sizes, int n_in,
                              void* d_out, int out_size, void* d_ws, size_t ws_size,
                              hipStream_t stream)
{
  (void)in_sizes; (void)n_in; (void)out_size;
  if (ws_size < (size_t)WS_TOTAL) return;

  const float* x    = (const float*)d_in[0];
  const float* eps  = (const float*)d_in[1];
  const float* Wee  = (const float*)d_in[2];
  const float* bee  = (const float*)d_in[3];
  const float* Wihf = (const float*)d_in[4];
  const float* Whhf = (const float*)d_in[5];
  const float* bihf = (const float*)d_in[6];
  const float* bhhf = (const float*)d_in[7];
  const float* Wihb = (const float*)d_in[8];
  const float* bihb = (const float*)d_in[10];
  const float* bhhb = (const float*)d_in[11];
  const float* Wenc = (const float*)d_in[12];
  const float* benc = (const float*)d_in[13];
  const float* Wz2h = (const float*)d_in[14];
  const float* bz2h = (const float*)d_in[15];
  const float* Wh2i = (const float*)d_in[16];
  const float* bh2i = (const float*)d_in[17];
  const float* Wihd = (const float*)d_in[18];
  const float* Whhd = (const float*)d_in[19];
  const float* bihd = (const float*)d_in[20];
  const float* bhhd = (const float*)d_in[21];
  const float* Wed  = (const float*)d_in[22];
  const float* bed  = (const float*)d_in[23];
  const float* Wdec = (const float*)d_in[24];
  const float* bdec = (const float*)d_in[25];
  char* ws = (char*)d_ws;

  pack_all<<<3193, 256, 0, stream>>>(Wihf, Whhf, Wihb, Wihd, Whhd, Wenc, Wz2h, Wh2i,
                                     Wdec, Wee, Wed, bed, bdec, ws);
  vae_main<<<128, 512, 0, stream>>>(x, eps, bee, bihf, bhhf, bihb, bhhb, bihd, bhhd,
                                    benc, bz2h, bh2i, bed, bdec, ws, (float*)d_out);
}